// Round 3
// baseline (1005.318 us; speedup 1.0000x reference)
//
#include <hip/hip_runtime.h>
#include <math.h>

#define NB 8
#define NC 512
#define NT 1024
#define SCALE 0.125f
#define SR 256   // t-rows per attention stripe
#define NSTR (NT / SR)
#define NEG_BIG (-3.0e38f)

__device__ __forceinline__ float bf2f(ushort u) {
    union { unsigned int i; float f; } v;
    v.i = ((unsigned int)u) << 16;
    return v.f;
}
__device__ __forceinline__ ushort f2bf(float f) {
    union { float f; unsigned int i; } v; v.f = f;
    unsigned int r = v.i + 0x7FFFu + ((v.i >> 16) & 1u);  // round-nearest-even
    return (ushort)(r >> 16);
}
__device__ __forceinline__ void bf4(const ushort4 u, float* f) {
    f[0] = bf2f(u.x); f[1] = bf2f(u.y); f[2] = bf2f(u.z); f[3] = bf2f(u.w);
}

// ---------------------------------------------------------------------------
// proj_in: y[b,t,d] = rot( sum_c W[d,c]*A[b,c,t] , phi[d] )
// A: fp32 [b][c][t].  W: fp32 [d][c].  phi: fp32 [d].
// Output token-major [b][t][d] bf16.
// ---------------------------------------------------------------------------
__global__ __launch_bounds__(256) void proj_in_kernel(
    const float* __restrict__ Are, const float* __restrict__ Aim,
    const float* __restrict__ W,   const float* __restrict__ phi,
    ushort* __restrict__ Ore, ushort* __restrict__ Oim)
{
    const int tid = threadIdx.x;
    const int t0 = blockIdx.x << 6;
    const int d0 = blockIdx.y << 6;
    const int b  = blockIdx.z;
    const size_t bo = (size_t)b * NC * NT;

    __shared__ float Asr[16][68];
    __shared__ float Asi[16][68];
    __shared__ float Bs[16][68];

    float accr[4][4] = {};
    float acci[4][4] = {};
    const int tq = tid >> 4;   // t micro-group
    const int dq = tid & 15;   // d micro-group

    for (int ck = 0; ck < NC; ck += 16) {
        {
            const int kk = tid >> 4, t4 = (tid & 15) << 2;
            size_t off = bo + (size_t)(ck + kk) * NT + t0 + t4;
            *(float4*)&Asr[kk][t4] = *(const float4*)(Are + off);
            *(float4*)&Asi[kk][t4] = *(const float4*)(Aim + off);
        }
        {
            const int dd = tid >> 2, cp = (tid & 3) << 2;
            const float4 fw = *(const float4*)(W + (size_t)(d0 + dd) * NC + ck + cp);
            Bs[cp + 0][dd] = fw.x; Bs[cp + 1][dd] = fw.y;
            Bs[cp + 2][dd] = fw.z; Bs[cp + 3][dd] = fw.w;
        }
        __syncthreads();
        #pragma unroll
        for (int kk = 0; kk < 16; ++kk) {
            const float4 arv = *(const float4*)&Asr[kk][tq << 2];
            const float4 aiv = *(const float4*)&Asi[kk][tq << 2];
            const float4 wv  = *(const float4*)&Bs[kk][dq << 2];
            const float ar[4] = {arv.x, arv.y, arv.z, arv.w};
            const float ai[4] = {aiv.x, aiv.y, aiv.z, aiv.w};
            const float wj[4] = {wv.x, wv.y, wv.z, wv.w};
            #pragma unroll
            for (int i = 0; i < 4; ++i)
                #pragma unroll
                for (int j = 0; j < 4; ++j) {
                    accr[i][j] = fmaf(ar[i], wj[j], accr[i][j]);
                    acci[i][j] = fmaf(ai[i], wj[j], acci[i][j]);
                }
        }
        __syncthreads();
    }

    float cs[4], sn[4];
    #pragma unroll
    for (int j = 0; j < 4; ++j) {
        const float ph = phi[d0 + (dq << 2) + j];
        cs[j] = cosf(ph); sn[j] = sinf(ph);
    }
    #pragma unroll
    for (int i = 0; i < 4; ++i) {
        const int t = t0 + (tq << 2) + i;
        const size_t off = bo + (size_t)t * NC + d0 + (dq << 2);
        ushort4 orv, oiv;
        orv.x = f2bf(accr[i][0] * cs[0] - acci[i][0] * sn[0]);
        orv.y = f2bf(accr[i][1] * cs[1] - acci[i][1] * sn[1]);
        orv.z = f2bf(accr[i][2] * cs[2] - acci[i][2] * sn[2]);
        orv.w = f2bf(accr[i][3] * cs[3] - acci[i][3] * sn[3]);
        oiv.x = f2bf(accr[i][0] * sn[0] + acci[i][0] * cs[0]);
        oiv.y = f2bf(accr[i][1] * sn[1] + acci[i][1] * cs[1]);
        oiv.z = f2bf(accr[i][2] * sn[2] + acci[i][2] * cs[2]);
        oiv.w = f2bf(accr[i][3] * sn[3] + acci[i][3] * cs[3]);
        *(ushort4*)(Ore + off) = orv;
        *(ushort4*)(Oim + off) = oiv;
    }
}

// ---------------------------------------------------------------------------
// proj_out: y[b,d,t] = rot( sum_c W[d,c]*A[b,t,c] , phi[d] )
// A: bf16 token-major [b][t][c].  Output: fp32 channel-major [b][d][t].
// ---------------------------------------------------------------------------
__global__ __launch_bounds__(256) void proj_out_kernel(
    const ushort* __restrict__ Are, const ushort* __restrict__ Aim,
    const float* __restrict__ W,   const float* __restrict__ phi,
    float* __restrict__ Ore, float* __restrict__ Oim)
{
    const int tid = threadIdx.x;
    const int t0 = blockIdx.x << 6;
    const int d0 = blockIdx.y << 6;
    const int b  = blockIdx.z;
    const size_t bo = (size_t)b * NC * NT;

    __shared__ float Asr[16][68];
    __shared__ float Asi[16][68];
    __shared__ float Bs[16][68];

    float accr[4][4] = {};
    float acci[4][4] = {};
    const int tq = tid >> 4;
    const int dq = tid & 15;

    for (int ck = 0; ck < NC; ck += 16) {
        {
            const int tt = tid >> 2, kp = (tid & 3) << 2;
            size_t off = bo + (size_t)(t0 + tt) * NC + ck + kp;
            float fr[4], fi[4];
            bf4(*(const ushort4*)(Are + off), fr);
            bf4(*(const ushort4*)(Aim + off), fi);
            #pragma unroll
            for (int w = 0; w < 4; ++w) { Asr[kp + w][tt] = fr[w]; Asi[kp + w][tt] = fi[w]; }
        }
        {
            const int dd = tid >> 2, cp = (tid & 3) << 2;
            const float4 fw = *(const float4*)(W + (size_t)(d0 + dd) * NC + ck + cp);
            Bs[cp + 0][dd] = fw.x; Bs[cp + 1][dd] = fw.y;
            Bs[cp + 2][dd] = fw.z; Bs[cp + 3][dd] = fw.w;
        }
        __syncthreads();
        #pragma unroll
        for (int kk = 0; kk < 16; ++kk) {
            const float4 arv = *(const float4*)&Asr[kk][tq << 2];
            const float4 aiv = *(const float4*)&Asi[kk][tq << 2];
            const float4 wv  = *(const float4*)&Bs[kk][dq << 2];
            const float ar[4] = {arv.x, arv.y, arv.z, arv.w};
            const float ai[4] = {aiv.x, aiv.y, aiv.z, aiv.w};
            const float wj[4] = {wv.x, wv.y, wv.z, wv.w};
            #pragma unroll
            for (int i = 0; i < 4; ++i)
                #pragma unroll
                for (int j = 0; j < 4; ++j) {
                    accr[i][j] = fmaf(ar[i], wj[j], accr[i][j]);
                    acci[i][j] = fmaf(ai[i], wj[j], acci[i][j]);
                }
        }
        __syncthreads();
    }

    float cs[4], sn[4];
    #pragma unroll
    for (int j = 0; j < 4; ++j) {
        const float ph = phi[d0 + (dq << 2) + j];
        cs[j] = cosf(ph); sn[j] = sinf(ph);
    }
    // direct [b][d][t] fp32 store: for each owned d (j), one float4 along t
    #pragma unroll
    for (int j = 0; j < 4; ++j) {
        const int d = d0 + (dq << 2) + j;
        const size_t off = bo + (size_t)d * NT + t0 + (tq << 2);
        float4 orv, oiv;
        orv.x = accr[0][j] * cs[j] - acci[0][j] * sn[j];
        orv.y = accr[1][j] * cs[j] - acci[1][j] * sn[j];
        orv.z = accr[2][j] * cs[j] - acci[2][j] * sn[j];
        orv.w = accr[3][j] * cs[j] - acci[3][j] * sn[j];
        oiv.x = accr[0][j] * sn[j] + acci[0][j] * cs[j];
        oiv.y = accr[1][j] * sn[j] + acci[1][j] * cs[j];
        oiv.z = accr[2][j] * sn[j] + acci[2][j] * cs[j];
        oiv.w = accr[3][j] * sn[j] + acci[3][j] * cs[j];
        *(float4*)(Ore + off) = orv;
        *(float4*)(Oim + off) = oiv;
    }
}

// ---------------------------------------------------------------------------
// scores (striped): S[b, t-s0, u] = 0.125*sum_d(qre*kre+qim*kim), NEG_BIG for u>t.
// Only tiles with u0 <= t0 do work.
// ---------------------------------------------------------------------------
__global__ __launch_bounds__(256) void scores_kernel(
    const ushort* __restrict__ Qre, const ushort* __restrict__ Qim,
    const ushort* __restrict__ Kre, const ushort* __restrict__ Kim,
    float* __restrict__ S, int s0)
{
    const int u0 = blockIdx.x << 6;
    const int t0 = s0 + (blockIdx.y << 6);
    if (u0 >= t0 + 64) return;  // entire tile masked
    const int b = blockIdx.z;
    const int tid = threadIdx.x;
    const size_t bo = (size_t)b * NC * NT;

    __shared__ float Qr[16][68], Qi[16][68], Kr[16][68], Ki[16][68];
    float acc[4][4] = {};
    const int tq = tid >> 4, uq = tid & 15;

    for (int dk = 0; dk < NC; dk += 16) {
        const int rr = tid >> 2, kp = (tid & 3) << 2;
        {
            size_t off = bo + (size_t)(t0 + rr) * NC + dk + kp;
            float fr[4], fi[4];
            bf4(*(const ushort4*)(Qre + off), fr);
            bf4(*(const ushort4*)(Qim + off), fi);
            #pragma unroll
            for (int w = 0; w < 4; ++w) { Qr[kp + w][rr] = fr[w]; Qi[kp + w][rr] = fi[w]; }
        }
        {
            size_t off = bo + (size_t)(u0 + rr) * NC + dk + kp;
            float fr[4], fi[4];
            bf4(*(const ushort4*)(Kre + off), fr);
            bf4(*(const ushort4*)(Kim + off), fi);
            #pragma unroll
            for (int w = 0; w < 4; ++w) { Kr[kp + w][rr] = fr[w]; Ki[kp + w][rr] = fi[w]; }
        }
        __syncthreads();
        #pragma unroll
        for (int kk = 0; kk < 16; ++kk) {
            const float4 qrv = *(const float4*)&Qr[kk][tq << 2];
            const float4 qiv = *(const float4*)&Qi[kk][tq << 2];
            const float4 krv = *(const float4*)&Kr[kk][uq << 2];
            const float4 kiv = *(const float4*)&Ki[kk][uq << 2];
            const float qr[4] = {qrv.x, qrv.y, qrv.z, qrv.w};
            const float qi[4] = {qiv.x, qiv.y, qiv.z, qiv.w};
            const float kr[4] = {krv.x, krv.y, krv.z, krv.w};
            const float ki[4] = {kiv.x, kiv.y, kiv.z, kiv.w};
            #pragma unroll
            for (int i = 0; i < 4; ++i)
                #pragma unroll
                for (int j = 0; j < 4; ++j) {
                    acc[i][j] = fmaf(qr[i], kr[j], acc[i][j]);
                    acc[i][j] = fmaf(qi[i], ki[j], acc[i][j]);
                }
        }
        __syncthreads();
    }
    #pragma unroll
    for (int i = 0; i < 4; ++i) {
        const int t = t0 + (tq << 2) + i;
        const int ub = u0 + (uq << 2);
        float4 ov;
        ov.x = (ub + 0 > t) ? NEG_BIG : acc[i][0] * SCALE;
        ov.y = (ub + 1 > t) ? NEG_BIG : acc[i][1] * SCALE;
        ov.z = (ub + 2 > t) ? NEG_BIG : acc[i][2] * SCALE;
        ov.w = (ub + 3 > t) ? NEG_BIG : acc[i][3] * SCALE;
        *(float4*)(S + (size_t)b * SR * NT + (size_t)(t - s0) * NT + ub) = ov;
    }
}

// ---------------------------------------------------------------------------
// softmax over u, in place on the stripe. Index-masks u<=t; writes p=0 else,
// so tiles never written by scores (poisoned ws) are ignored. All-finite math.
// ---------------------------------------------------------------------------
__global__ __launch_bounds__(256) void softmax_kernel(float* __restrict__ S, int s0)
{
    const int lt = blockIdx.x;          // local row in stripe
    const int t = s0 + lt;
    const int b = blockIdx.y;
    float* row = S + (size_t)b * SR * NT + (size_t)lt * NT;
    const int tid = threadIdx.x;
    const int u0 = tid << 2;
    const float4 sv = *(const float4*)(row + u0);
    const float s[4] = {sv.x, sv.y, sv.z, sv.w};

    float m = NEG_BIG;
    #pragma unroll
    for (int i = 0; i < 4; ++i) if (u0 + i <= t) m = fmaxf(m, s[i]);
    #pragma unroll
    for (int off = 32; off > 0; off >>= 1) m = fmaxf(m, __shfl_xor(m, off, 64));

    __shared__ float rm[4], rs[4];
    const int wv = tid >> 6, ln = tid & 63;
    if (ln == 0) rm[wv] = m;
    __syncthreads();
    m = fmaxf(fmaxf(rm[0], rm[1]), fmaxf(rm[2], rm[3]));

    float e[4]; float ls = 0.f;
    #pragma unroll
    for (int i = 0; i < 4; ++i) {
        e[i] = (u0 + i <= t) ? __expf(s[i] - m) : 0.f;
        ls += e[i];
    }
    #pragma unroll
    for (int off = 32; off > 0; off >>= 1) ls += __shfl_xor(ls, off, 64);
    if (ln == 0) rs[wv] = ls;
    __syncthreads();
    const float inv = 1.0f / (rs[0] + rs[1] + rs[2] + rs[3]);
    float4 ov = make_float4(e[0] * inv, e[1] * inv, e[2] * inv, e[3] * inv);
    *(float4*)(row + u0) = ov;
}

// ---------------------------------------------------------------------------
// pv (striped): O[b,t,c] = sum_{u<=t} P[b,t,u] * V[b,u,c], re & im.
// O aliases the Q buffers (q rows of this stripe are already consumed).
// ---------------------------------------------------------------------------
__global__ __launch_bounds__(256) void pv_kernel(
    const float* __restrict__ S, const ushort* __restrict__ Vre,
    const ushort* __restrict__ Vim,
    ushort* __restrict__ Ore, ushort* __restrict__ Oim, int s0)
{
    const int c0 = blockIdx.x << 6;
    const int lt0 = blockIdx.y << 6;        // local t-tile in stripe
    const int t0 = s0 + lt0;
    const int b = blockIdx.z;
    const int tid = threadIdx.x;
    const size_t bo = (size_t)b * NC * NT;
    const float* Sb = S + (size_t)b * SR * NT;

    __shared__ float Ps[16][68], Vr[16][68], Vi[16][68];
    float accr[4][4] = {}, acci[4][4] = {};
    const int tq = tid >> 4, cq = tid & 15;

    const int ulim = t0 + 64;
    for (int uk = 0; uk < ulim; uk += 16) {
        {
            const int tt = tid >> 2, kp = (tid & 3) << 2;
            const float4 p = *(const float4*)(Sb + (size_t)(lt0 + tt) * NT + uk + kp);
            Ps[kp + 0][tt] = p.x; Ps[kp + 1][tt] = p.y;
            Ps[kp + 2][tt] = p.z; Ps[kp + 3][tt] = p.w;
        }
        {
            const int kk = tid >> 4, c4 = (tid & 15) << 2;
            size_t off = bo + (size_t)(uk + kk) * NC + c0 + c4;
            float fr[4], fi[4];
            bf4(*(const ushort4*)(Vre + off), fr);
            bf4(*(const ushort4*)(Vim + off), fi);
            *(float4*)&Vr[kk][c4] = make_float4(fr[0], fr[1], fr[2], fr[3]);
            *(float4*)&Vi[kk][c4] = make_float4(fi[0], fi[1], fi[2], fi[3]);
        }
        __syncthreads();
        #pragma unroll
        for (int kk = 0; kk < 16; ++kk) {
            const float4 pv = *(const float4*)&Ps[kk][tq << 2];
            const float4 vrv = *(const float4*)&Vr[kk][cq << 2];
            const float4 viv = *(const float4*)&Vi[kk][cq << 2];
            const float p[4]  = {pv.x, pv.y, pv.z, pv.w};
            const float vr[4] = {vrv.x, vrv.y, vrv.z, vrv.w};
            const float vi[4] = {viv.x, viv.y, viv.z, viv.w};
            #pragma unroll
            for (int i = 0; i < 4; ++i)
                #pragma unroll
                for (int j = 0; j < 4; ++j) {
                    accr[i][j] = fmaf(p[i], vr[j], accr[i][j]);
                    acci[i][j] = fmaf(p[i], vi[j], acci[i][j]);
                }
        }
        __syncthreads();
    }
    #pragma unroll
    for (int i = 0; i < 4; ++i) {
        const int t = t0 + (tq << 2) + i;
        const size_t off = bo + (size_t)t * NC + c0 + (cq << 2);
        ushort4 orv, oiv;
        orv.x = f2bf(accr[i][0]); orv.y = f2bf(accr[i][1]);
        orv.z = f2bf(accr[i][2]); orv.w = f2bf(accr[i][3]);
        oiv.x = f2bf(acci[i][0]); oiv.y = f2bf(acci[i][1]);
        oiv.z = f2bf(acci[i][2]); oiv.w = f2bf(acci[i][3]);
        *(ushort4*)(Ore + off) = orv;
        *(ushort4*)(Oim + off) = oiv;
    }
}

extern "C" void kernel_launch(void* const* d_in, const int* in_sizes, int n_in,
                              void* d_out, int out_size, void* d_ws, size_t ws_size,
                              hipStream_t stream) {
    (void)in_sizes; (void)n_in; (void)out_size; (void)ws_size;
    const float* z_re  = (const float*)d_in[0];
    const float* z_im  = (const float*)d_in[1];
    const float* Wq    = (const float*)d_in[2];
    const float* phi_q = (const float*)d_in[3];
    const float* Wk    = (const float*)d_in[4];
    const float* phi_k = (const float*)d_in[5];
    const float* Wv    = (const float*)d_in[6];
    const float* phi_v = (const float*)d_in[7];
    const float* Wo    = (const float*)d_in[8];
    const float* phi_o = (const float*)d_in[9];

    const size_t NE = (size_t)NB * NC * NT;  // 4,194,304 elems per component
    ushort* ws  = (ushort*)d_ws;
    ushort* qre = ws + 0 * NE; ushort* qim = ws + 1 * NE;   // later aliased as O
    ushort* kre = ws + 2 * NE; ushort* kim = ws + 3 * NE;
    ushort* vre = ws + 4 * NE; ushort* vim = ws + 5 * NE;
    float*  S   = (float*)(ws + 6 * NE);     // 8 MiB fp32 stripe scores
    // total ws use: 6*8 MiB + 8 MiB = 56 MiB

    const dim3 blk(256);
    const dim3 gproj(NT / 64, NC / 64, NB);
    hipLaunchKernelGGL(proj_in_kernel, gproj, blk, 0, stream, z_re, z_im, Wq, phi_q, qre, qim);
    hipLaunchKernelGGL(proj_in_kernel, gproj, blk, 0, stream, z_re, z_im, Wk, phi_k, kre, kim);
    hipLaunchKernelGGL(proj_in_kernel, gproj, blk, 0, stream, z_re, z_im, Wv, phi_v, vre, vim);

    const dim3 gsc(NT / 64, SR / 64, NB);
    const dim3 gsm(SR, NB);
    const dim3 gpv(NC / 64, SR / 64, NB);
    for (int s = 0; s < NSTR; ++s) {
        const int s0 = s * SR;
        hipLaunchKernelGGL(scores_kernel, gsc, blk, 0, stream, qre, qim, kre, kim, S, s0);
        hipLaunchKernelGGL(softmax_kernel, gsm, blk, 0, stream, S, s0);
        // O aliases Q buffers: rows [s0, s0+SR) of q are dead after scores(s0)
        hipLaunchKernelGGL(pv_kernel, gpv, blk, 0, stream, S, vre, vim, qre, qim, s0);
    }

    float* outRe = (float*)d_out;
    float* outIm = outRe + NE;
    hipLaunchKernelGGL(proj_out_kernel, gproj, blk, 0, stream, qre, qim, Wo, phi_o, outRe, outIm);
}

// Round 4
// 414.290 us; speedup vs baseline: 2.4266x; 2.4266x over previous
//
#include <hip/hip_runtime.h>
#include <math.h>

#define NB 8
#define NC 512
#define NT 1024
#define SCALE 0.125f
#define SR 128   // t-rows per attention stripe
#define NSTR (NT / SR)
#define NEG_BIG (-3.0e38f)
#define LDW 40   // LDS row stride in shorts for 32-elem bf16 rows (80B: keeps b128 aligned, <=2-way banks)

typedef __attribute__((ext_vector_type(8))) short short8v;   // 8 bf16 = 4 VGPRs (A/B frag)
typedef __attribute__((ext_vector_type(4))) float float4v;   // C/D frag
#define MFMA_BF16(A, B, C) __builtin_amdgcn_mfma_f32_16x16x32_bf16(A, B, C, 0, 0, 0)

__device__ __forceinline__ float bf2f(ushort u) {
    union { unsigned int i; float f; } v;
    v.i = ((unsigned int)u) << 16;
    return v.f;
}
__device__ __forceinline__ ushort f2bf(float f) {
    union { float f; unsigned int i; } v; v.f = f;
    unsigned int r = v.i + 0x7FFFu + ((v.i >> 16) & 1u);  // round-nearest-even
    return (ushort)(r >> 16);
}

// ---------------------------------------------------------------------------
// proj_qkv: one pass over z computes q,k (token-major [b][t][d] bf16) and
// v (channel-major [b][d][t] bf16), each rotated by its phi.
// q/k: D[m=t][n=d] = sum_c z[t][c] * W[d][c]   (A=z, B=W)
// v:   D[m=d][n=t] = sum_c W[d][c] * z[t][c]   (A=W, B=z)  -> channel-major
// Frag lane maps are identical for A and B (idx16=lane&15, k=quad*8+j), so
// the same LDS reads feed both roles.
// ---------------------------------------------------------------------------
__global__ __launch_bounds__(256) void proj_qkv_kernel(
    const float* __restrict__ zre, const float* __restrict__ zim,
    const float* __restrict__ Wq,  const float* __restrict__ phiq,
    const float* __restrict__ Wk,  const float* __restrict__ phik,
    const float* __restrict__ Wv,  const float* __restrict__ phiv,
    ushort* __restrict__ qre, ushort* __restrict__ qim,
    ushort* __restrict__ kre, ushort* __restrict__ kim,
    ushort* __restrict__ vre, ushort* __restrict__ vim)
{
    const int tid = threadIdx.x;
    const int t0 = blockIdx.x << 6;
    const int d0 = blockIdx.y << 6;
    const int b  = blockIdx.z;
    const size_t bo = (size_t)b * NC * NT;

    __shared__ ushort Zr[64 * LDW];
    __shared__ ushort Zi[64 * LDW];
    __shared__ ushort Wsh[3][64 * LDW];

    float4v accq[2][2][2] = {};   // [comp][i(t16)][j(d16)]
    float4v acck[2][2][2] = {};
    float4v accv[2][2][2] = {};   // [comp][j(d16)][i(t16)]

    const int lane = tid & 63;
    const int wA = ((tid >> 6) & 1) << 5;   // t-half
    const int wB = ((tid >> 6) >> 1) << 5;  // d-half
    const int l15 = lane & 15;
    const int quad = lane >> 4;

    const int zc2  = (tid & 15) << 1;   // c pair base within 32-chunk
    const int zt4  = (tid >> 4) << 2;   // t base (4 rows)
    const int wrow = tid >> 2;          // W d-row
    const int wcol = (tid & 3) << 3;    // W c base (8 elems)

    const float* WmP[3] = {Wq, Wk, Wv};

    for (int c0 = 0; c0 < NC; c0 += 32) {
        // --- stage z (fp32 [c][t]) -> bf16 LDS [t][c] (transposed) ---
        {
            const float* zp = zre + bo + (size_t)(c0 + zc2) * NT + t0 + zt4;
            float4 a = *(const float4*)zp;
            float4 c2 = *(const float4*)(zp + NT);
            ushort2 p;
            p.x = f2bf(a.x); p.y = f2bf(c2.x); *(ushort2*)&Zr[(zt4 + 0) * LDW + zc2] = p;
            p.x = f2bf(a.y); p.y = f2bf(c2.y); *(ushort2*)&Zr[(zt4 + 1) * LDW + zc2] = p;
            p.x = f2bf(a.z); p.y = f2bf(c2.z); *(ushort2*)&Zr[(zt4 + 2) * LDW + zc2] = p;
            p.x = f2bf(a.w); p.y = f2bf(c2.w); *(ushort2*)&Zr[(zt4 + 3) * LDW + zc2] = p;
            zp = zim + bo + (size_t)(c0 + zc2) * NT + t0 + zt4;
            a = *(const float4*)zp;
            c2 = *(const float4*)(zp + NT);
            p.x = f2bf(a.x); p.y = f2bf(c2.x); *(ushort2*)&Zi[(zt4 + 0) * LDW + zc2] = p;
            p.x = f2bf(a.y); p.y = f2bf(c2.y); *(ushort2*)&Zi[(zt4 + 1) * LDW + zc2] = p;
            p.x = f2bf(a.z); p.y = f2bf(c2.z); *(ushort2*)&Zi[(zt4 + 2) * LDW + zc2] = p;
            p.x = f2bf(a.w); p.y = f2bf(c2.w); *(ushort2*)&Zi[(zt4 + 3) * LDW + zc2] = p;
        }
        // --- stage W (fp32 [d][c]) -> bf16 LDS [d][c] ---
        #pragma unroll
        for (int m = 0; m < 3; ++m) {
            const float* wp = WmP[m] + (size_t)(d0 + wrow) * NC + c0 + wcol;
            const float4 a = *(const float4*)wp;
            const float4 c2 = *(const float4*)(wp + 4);
            short8v v8;
            v8[0] = (short)f2bf(a.x);  v8[1] = (short)f2bf(a.y);
            v8[2] = (short)f2bf(a.z);  v8[3] = (short)f2bf(a.w);
            v8[4] = (short)f2bf(c2.x); v8[5] = (short)f2bf(c2.y);
            v8[6] = (short)f2bf(c2.z); v8[7] = (short)f2bf(c2.w);
            *(short8v*)&Wsh[m][wrow * LDW + wcol] = v8;
        }
        __syncthreads();

        short8v zf[2][2], wf[3][2];
        #pragma unroll
        for (int i = 0; i < 2; ++i) {
            zf[0][i] = *(const short8v*)&Zr[(wA + i * 16 + l15) * LDW + quad * 8];
            zf[1][i] = *(const short8v*)&Zi[(wA + i * 16 + l15) * LDW + quad * 8];
        }
        #pragma unroll
        for (int m = 0; m < 3; ++m)
            #pragma unroll
            for (int j = 0; j < 2; ++j)
                wf[m][j] = *(const short8v*)&Wsh[m][(wB + j * 16 + l15) * LDW + quad * 8];

        #pragma unroll
        for (int cmp = 0; cmp < 2; ++cmp)
            #pragma unroll
            for (int i = 0; i < 2; ++i)
                #pragma unroll
                for (int j = 0; j < 2; ++j) {
                    accq[cmp][i][j] = MFMA_BF16(zf[cmp][i], wf[0][j], accq[cmp][i][j]);
                    acck[cmp][i][j] = MFMA_BF16(zf[cmp][i], wf[1][j], acck[cmp][i][j]);
                    accv[cmp][j][i] = MFMA_BF16(wf[2][j], zf[cmp][i], accv[cmp][j][i]);
                }
        __syncthreads();
    }

    // --- epilogue q/k: token-major [b][t][d], C/D layout col=lane&15(d), row=quad*4+r(t) ---
    #pragma unroll
    for (int j = 0; j < 2; ++j) {
        const int d = d0 + wB + j * 16 + l15;
        const float pq = phiq[d], pk = phik[d];
        const float cq = cosf(pq), sq = sinf(pq);
        const float ck = cosf(pk), sk = sinf(pk);
        #pragma unroll
        for (int i = 0; i < 2; ++i)
            #pragma unroll
            for (int r = 0; r < 4; ++r) {
                const int t = t0 + wA + i * 16 + quad * 4 + r;
                const size_t off = bo + (size_t)t * NC + d;
                const float qr2 = accq[0][i][j][r], qi2 = accq[1][i][j][r];
                qre[off] = f2bf(qr2 * cq - qi2 * sq);
                qim[off] = f2bf(qr2 * sq + qi2 * cq);
                const float kr2 = acck[0][i][j][r], ki2 = acck[1][i][j][r];
                kre[off] = f2bf(kr2 * ck - ki2 * sk);
                kim[off] = f2bf(kr2 * sk + ki2 * ck);
            }
    }
    // --- epilogue v: channel-major [b][d][t], col=lane&15(t), row=quad*4+r(d) ---
    #pragma unroll
    for (int j = 0; j < 2; ++j)
        #pragma unroll
        for (int r = 0; r < 4; ++r) {
            const int d = d0 + wB + j * 16 + quad * 4 + r;
            const float pv_ = phiv[d];
            const float cv = cosf(pv_), sv = sinf(pv_);
            #pragma unroll
            for (int i = 0; i < 2; ++i) {
                const int t = t0 + wA + i * 16 + l15;
                const size_t off = bo + (size_t)d * NT + t;
                const float vr2 = accv[0][j][i][r], vi2 = accv[1][j][i][r];
                vre[off] = f2bf(vr2 * cv - vi2 * sv);
                vim[off] = f2bf(vr2 * sv + vi2 * cv);
            }
        }
}

// ---------------------------------------------------------------------------
// scores: S[t][u] = 0.125*(Qre·Kre^T + Qim·Kim^T), NEG_BIG above diagonal.
// A=Q token-major, B=K token-major. Only u-tiles <= t-tile launched do work.
// ---------------------------------------------------------------------------
__global__ __launch_bounds__(256) void scores_mfma_kernel(
    const ushort* __restrict__ Qre, const ushort* __restrict__ Qim,
    const ushort* __restrict__ Kre, const ushort* __restrict__ Kim,
    float* __restrict__ S, int s0)
{
    const int u0 = blockIdx.x << 6;
    const int t0 = s0 + (blockIdx.y << 6);
    if (u0 > t0) return;
    const int b = blockIdx.z;
    const int tid = threadIdx.x;
    const size_t bo = (size_t)b * NC * NT;

    __shared__ ushort Qs[2][64 * LDW];
    __shared__ ushort Ks[2][64 * LDW];
    float4v acc[2][2] = {};   // [i(t16)][j(u16)]

    const int lane = tid & 63;
    const int wA = ((tid >> 6) & 1) << 5;
    const int wB = ((tid >> 6) >> 1) << 5;
    const int l15 = lane & 15;
    const int quad = lane >> 4;
    const int sr_ = tid >> 2, sc = (tid & 3) << 3;

    for (int c0 = 0; c0 < NC; c0 += 32) {
        *(uint4*)&Qs[0][sr_ * LDW + sc] = *(const uint4*)(Qre + bo + (size_t)(t0 + sr_) * NC + c0 + sc);
        *(uint4*)&Qs[1][sr_ * LDW + sc] = *(const uint4*)(Qim + bo + (size_t)(t0 + sr_) * NC + c0 + sc);
        *(uint4*)&Ks[0][sr_ * LDW + sc] = *(const uint4*)(Kre + bo + (size_t)(u0 + sr_) * NC + c0 + sc);
        *(uint4*)&Ks[1][sr_ * LDW + sc] = *(const uint4*)(Kim + bo + (size_t)(u0 + sr_) * NC + c0 + sc);
        __syncthreads();
        short8v qf[2][2], kf[2][2];
        #pragma unroll
        for (int i = 0; i < 2; ++i) {
            qf[0][i] = *(const short8v*)&Qs[0][(wA + i * 16 + l15) * LDW + quad * 8];
            qf[1][i] = *(const short8v*)&Qs[1][(wA + i * 16 + l15) * LDW + quad * 8];
            kf[0][i] = *(const short8v*)&Ks[0][(wB + i * 16 + l15) * LDW + quad * 8];
            kf[1][i] = *(const short8v*)&Ks[1][(wB + i * 16 + l15) * LDW + quad * 8];
        }
        #pragma unroll
        for (int i = 0; i < 2; ++i)
            #pragma unroll
            for (int j = 0; j < 2; ++j) {
                acc[i][j] = MFMA_BF16(qf[0][i], kf[0][j], acc[i][j]);
                acc[i][j] = MFMA_BF16(qf[1][i], kf[1][j], acc[i][j]);
            }
        __syncthreads();
    }
    #pragma unroll
    for (int i = 0; i < 2; ++i)
        #pragma unroll
        for (int j = 0; j < 2; ++j)
            #pragma unroll
            for (int r = 0; r < 4; ++r) {
                const int t = t0 + wA + i * 16 + quad * 4 + r;
                const int u = u0 + wB + j * 16 + l15;
                S[((size_t)b * SR + (t - s0)) * NT + u] = (u > t) ? NEG_BIG : acc[i][j][r] * SCALE;
            }
}

// ---------------------------------------------------------------------------
// softmax over u (stripe), fp32 in -> bf16 P out. Index-masks u<=t so tiles
// never written by scores (poison) are ignored; writes p=0 there.
// ---------------------------------------------------------------------------
__global__ __launch_bounds__(256) void softmax_kernel(
    const float* __restrict__ S, ushort* __restrict__ P, int s0)
{
    const int lt = blockIdx.x;
    const int t = s0 + lt;
    const int b = blockIdx.y;
    const float* row = S + ((size_t)b * SR + lt) * NT;
    ushort* prow = P + ((size_t)b * SR + lt) * NT;
    const int tid = threadIdx.x;
    const int u0 = tid << 2;
    const float4 sv = *(const float4*)(row + u0);
    const float s[4] = {sv.x, sv.y, sv.z, sv.w};

    float m = NEG_BIG;
    #pragma unroll
    for (int i = 0; i < 4; ++i) if (u0 + i <= t) m = fmaxf(m, s[i]);
    #pragma unroll
    for (int off = 32; off > 0; off >>= 1) m = fmaxf(m, __shfl_xor(m, off, 64));

    __shared__ float rm[4], rs[4];
    const int wv = tid >> 6, ln = tid & 63;
    if (ln == 0) rm[wv] = m;
    __syncthreads();
    m = fmaxf(fmaxf(rm[0], rm[1]), fmaxf(rm[2], rm[3]));

    float e[4]; float ls = 0.f;
    #pragma unroll
    for (int i = 0; i < 4; ++i) {
        e[i] = (u0 + i <= t) ? __expf(s[i] - m) : 0.f;
        ls += e[i];
    }
    #pragma unroll
    for (int off = 32; off > 0; off >>= 1) ls += __shfl_xor(ls, off, 64);
    if (ln == 0) rs[wv] = ls;
    __syncthreads();
    const float inv = 1.0f / (rs[0] + rs[1] + rs[2] + rs[3]);
    ushort4 ov;
    ov.x = f2bf(e[0] * inv); ov.y = f2bf(e[1] * inv);
    ov.z = f2bf(e[2] * inv); ov.w = f2bf(e[3] * inv);
    *(ushort4*)(prow + u0) = ov;
}

// ---------------------------------------------------------------------------
// pv: O[t][c] = sum_{u} P[t][u] * V[u][c]  (A=P bf16, B=V channel-major bf16)
// O written token-major [b][t][c] bf16 (aliases q buffers).
// ---------------------------------------------------------------------------
__global__ __launch_bounds__(256) void pv_mfma_kernel(
    const ushort* __restrict__ P,
    const ushort* __restrict__ Vre, const ushort* __restrict__ Vim,
    ushort* __restrict__ Ore, ushort* __restrict__ Oim, int s0)
{
    const int c0 = blockIdx.x << 6;
    const int lt0 = blockIdx.y << 6;
    const int t0 = s0 + lt0;
    const int b = blockIdx.z;
    const int tid = threadIdx.x;
    const size_t bo = (size_t)b * NC * NT;
    const size_t pb = ((size_t)b * SR + lt0) * NT;

    __shared__ ushort Ps[64 * LDW];
    __shared__ ushort Vs[2][64 * LDW];
    float4v acc[2][2][2] = {};   // [comp][i(t16)][j(c16)]

    const int lane = tid & 63;
    const int wA = ((tid >> 6) & 1) << 5;
    const int wB = ((tid >> 6) >> 1) << 5;
    const int l15 = lane & 15;
    const int quad = lane >> 4;
    const int sr_ = tid >> 2, sc = (tid & 3) << 3;

    const int ulim = t0 + 64;
    for (int u0 = 0; u0 < ulim; u0 += 32) {
        *(uint4*)&Ps[sr_ * LDW + sc] = *(const uint4*)(P + pb + (size_t)sr_ * NT + u0 + sc);
        *(uint4*)&Vs[0][sr_ * LDW + sc] = *(const uint4*)(Vre + bo + (size_t)(c0 + sr_) * NT + u0 + sc);
        *(uint4*)&Vs[1][sr_ * LDW + sc] = *(const uint4*)(Vim + bo + (size_t)(c0 + sr_) * NT + u0 + sc);
        __syncthreads();
        short8v pf[2], vf[2][2];
        #pragma unroll
        for (int i = 0; i < 2; ++i) {
            pf[i] = *(const short8v*)&Ps[(wA + i * 16 + l15) * LDW + quad * 8];
            vf[0][i] = *(const short8v*)&Vs[0][(wB + i * 16 + l15) * LDW + quad * 8];
            vf[1][i] = *(const short8v*)&Vs[1][(wB + i * 16 + l15) * LDW + quad * 8];
        }
        #pragma unroll
        for (int i = 0; i < 2; ++i)
            #pragma unroll
            for (int j = 0; j < 2; ++j) {
                acc[0][i][j] = MFMA_BF16(pf[i], vf[0][j], acc[0][i][j]);
                acc[1][i][j] = MFMA_BF16(pf[i], vf[1][j], acc[1][i][j]);
            }
        __syncthreads();
    }
    #pragma unroll
    for (int i = 0; i < 2; ++i)
        #pragma unroll
        for (int j = 0; j < 2; ++j)
            #pragma unroll
            for (int r = 0; r < 4; ++r) {
                const int t = t0 + wA + i * 16 + quad * 4 + r;
                const int c = c0 + wB + j * 16 + l15;
                const size_t off = bo + (size_t)t * NC + c;
                Ore[off] = f2bf(acc[0][i][j][r]);
                Oim[off] = f2bf(acc[1][i][j][r]);
            }
}

// ---------------------------------------------------------------------------
// proj_out: y[d][t] = rot( sum_c Wo[d][c] * O[t][c], phi_o[d] ), fp32 out to
// d_out [b][d][t]. Operand-swapped (A=Wo, B=O) so stores are lane-contiguous.
// ---------------------------------------------------------------------------
__global__ __launch_bounds__(256) void proj_out_kernel(
    const ushort* __restrict__ Ore, const ushort* __restrict__ Oim,
    const float* __restrict__ Wo, const float* __restrict__ phio,
    float* __restrict__ outRe, float* __restrict__ outIm)
{
    const int d0 = blockIdx.x << 6;
    const int t0 = blockIdx.y << 6;
    const int b = blockIdx.z;
    const int tid = threadIdx.x;
    const size_t bo = (size_t)b * NC * NT;

    __shared__ ushort WoS[64 * LDW];
    __shared__ ushort Os[2][64 * LDW];
    float4v acc[2][2][2] = {};   // [comp][i(d16)][j(t16)]

    const int lane = tid & 63;
    const int wA = ((tid >> 6) & 1) << 5;   // d-half
    const int wB = ((tid >> 6) >> 1) << 5;  // t-half
    const int l15 = lane & 15;
    const int quad = lane >> 4;
    const int wrow = tid >> 2, wcol = (tid & 3) << 3;

    for (int c0 = 0; c0 < NC; c0 += 32) {
        {
            const float* wp = Wo + (size_t)(d0 + wrow) * NC + c0 + wcol;
            const float4 a = *(const float4*)wp;
            const float4 c2 = *(const float4*)(wp + 4);
            short8v v8;
            v8[0] = (short)f2bf(a.x);  v8[1] = (short)f2bf(a.y);
            v8[2] = (short)f2bf(a.z);  v8[3] = (short)f2bf(a.w);
            v8[4] = (short)f2bf(c2.x); v8[5] = (short)f2bf(c2.y);
            v8[6] = (short)f2bf(c2.z); v8[7] = (short)f2bf(c2.w);
            *(short8v*)&WoS[wrow * LDW + wcol] = v8;
        }
        *(uint4*)&Os[0][wrow * LDW + wcol] = *(const uint4*)(Ore + bo + (size_t)(t0 + wrow) * NC + c0 + wcol);
        *(uint4*)&Os[1][wrow * LDW + wcol] = *(const uint4*)(Oim + bo + (size_t)(t0 + wrow) * NC + c0 + wcol);
        __syncthreads();
        short8v wf[2], of[2][2];
        #pragma unroll
        for (int i = 0; i < 2; ++i) {
            wf[i] = *(const short8v*)&WoS[(wA + i * 16 + l15) * LDW + quad * 8];
            of[0][i] = *(const short8v*)&Os[0][(wB + i * 16 + l15) * LDW + quad * 8];
            of[1][i] = *(const short8v*)&Os[1][(wB + i * 16 + l15) * LDW + quad * 8];
        }
        #pragma unroll
        for (int i = 0; i < 2; ++i)
            #pragma unroll
            for (int j = 0; j < 2; ++j) {
                acc[0][i][j] = MFMA_BF16(wf[i], of[0][j], acc[0][i][j]);
                acc[1][i][j] = MFMA_BF16(wf[i], of[1][j], acc[1][i][j]);
            }
        __syncthreads();
    }
    #pragma unroll
    for (int i = 0; i < 2; ++i)
        #pragma unroll
        for (int r = 0; r < 4; ++r) {
            const int d = d0 + wA + i * 16 + quad * 4 + r;
            const float ph = phio[d];
            const float cs = cosf(ph), sn = sinf(ph);
            #pragma unroll
            for (int j = 0; j < 2; ++j) {
                const int t = t0 + wB + j * 16 + l15;
                const float re2 = acc[0][i][j][r], im2 = acc[1][i][j][r];
                const size_t off = bo + (size_t)d * NT + t;
                outRe[off] = re2 * cs - im2 * sn;
                outIm[off] = re2 * sn + im2 * cs;
            }
        }
}

extern "C" void kernel_launch(void* const* d_in, const int* in_sizes, int n_in,
                              void* d_out, int out_size, void* d_ws, size_t ws_size,
                              hipStream_t stream) {
    (void)in_sizes; (void)n_in; (void)out_size; (void)ws_size;
    const float* z_re  = (const float*)d_in[0];
    const float* z_im  = (const float*)d_in[1];
    const float* Wq    = (const float*)d_in[2];
    const float* phi_q = (const float*)d_in[3];
    const float* Wk    = (const float*)d_in[4];
    const float* phi_k = (const float*)d_in[5];
    const float* Wv    = (const float*)d_in[6];
    const float* phi_v = (const float*)d_in[7];
    const float* Wo    = (const float*)d_in[8];
    const float* phi_o = (const float*)d_in[9];

    const size_t NE = (size_t)NB * NC * NT;      // 4,194,304
    const size_t SSZ = (size_t)NB * SR * NT;     // stripe elems: 1,048,576
    ushort* ws  = (ushort*)d_ws;
    ushort* qre = ws + 0 * NE; ushort* qim = ws + 1 * NE;   // aliased as O after scores
    ushort* kre = ws + 2 * NE; ushort* kim = ws + 3 * NE;
    ushort* vre = ws + 4 * NE; ushort* vim = ws + 5 * NE;   // channel-major
    float*  S   = (float*)(ws + 6 * NE);                    // 4 MiB fp32 stripe
    ushort* P   = (ushort*)(S + SSZ);                       // 2 MiB bf16 stripe
    // total: 48 MiB + 4 MiB + 2 MiB = 54 MiB (<= 56 MiB proven in R3)

    const dim3 blk(256);
    hipLaunchKernelGGL(proj_qkv_kernel, dim3(NT / 64, NC / 64, NB), blk, 0, stream,
                       z_re, z_im, Wq, phi_q, Wk, phi_k, Wv, phi_v,
                       qre, qim, kre, kim, vre, vim);

    const dim3 gsc(NT / 64, SR / 64, NB);
    const dim3 gsm(SR, NB);
    const dim3 gpv(NC / 64, SR / 64, NB);
    for (int s = 0; s < NSTR; ++s) {
        const int s0 = s * SR;
        hipLaunchKernelGGL(scores_mfma_kernel, gsc, blk, 0, stream, qre, qim, kre, kim, S, s0);
        hipLaunchKernelGGL(softmax_kernel, gsm, blk, 0, stream, S, P, s0);
        hipLaunchKernelGGL(pv_mfma_kernel, gpv, blk, 0, stream, P, vre, vim, qre, qim, s0);
    }

    float* outRe = (float*)d_out;
    float* outIm = outRe + NE;
    hipLaunchKernelGGL(proj_out_kernel, dim3(NC / 64, NT / 64, NB), blk, 0, stream,
                       qre, qim, Wo, phi_o, outRe, outIm);
}

// Round 5
// 287.707 us; speedup vs baseline: 3.4942x; 1.4400x over previous
//
#include <hip/hip_runtime.h>
#include <math.h>

#define NB 8
#define NC 512
#define NT 1024
#define SCALE 0.125f
#define NEG_BIG (-3.0e38f)
#define LDW 40   // LDS row stride in shorts (80B: 16B-aligned, conflict-benign)

typedef __attribute__((ext_vector_type(8))) short short8v;   // 8 bf16 (A/B frag)
typedef __attribute__((ext_vector_type(4))) float float4v;   // C/D frag
#define MFMA_BF16(A, B, C) __builtin_amdgcn_mfma_f32_16x16x32_bf16(A, B, C, 0, 0, 0)

__device__ __forceinline__ ushort f2bf(float f) {
    union { float f; unsigned int i; } v; v.f = f;
    unsigned int r = v.i + 0x7FFFu + ((v.i >> 16) & 1u);  // RNE
    return (ushort)(r >> 16);
}

// ---------------------------------------------------------------------------
// prep_z: z fp32 [b][c][t] -> Z bf16 token-major [comp][b][t][c]
// ---------------------------------------------------------------------------
__global__ __launch_bounds__(256) void prep_z_kernel(
    const float* __restrict__ zre, const float* __restrict__ zim,
    ushort* __restrict__ Z)
{
    const int t0 = blockIdx.x << 6, c0 = blockIdx.y << 6;
    const int bz = blockIdx.z, b = bz & 7, comp = bz >> 3;
    const float* src = (comp ? zim : zre) + (size_t)b * NC * NT;
    ushort* dst = Z + (size_t)(comp * NB + b) * NT * NC;
    const int tid = threadIdx.x;

    __shared__ ushort T[64][72];
    #pragma unroll
    for (int r = 0; r < 4; ++r) {
        const int cl = (tid >> 4) + r * 16;
        const int t4 = (tid & 15) << 2;
        const float4 v = *(const float4*)(src + (size_t)(c0 + cl) * NT + t0 + t4);
        T[t4 + 0][cl] = f2bf(v.x); T[t4 + 1][cl] = f2bf(v.y);
        T[t4 + 2][cl] = f2bf(v.z); T[t4 + 3][cl] = f2bf(v.w);
    }
    __syncthreads();
    const int tl = tid >> 2, cc = (tid & 3) << 4;
    ushort* op = dst + (size_t)(t0 + tl) * NC + c0 + cc;
    *(uint4*)op       = *(const uint4*)&T[tl][cc];
    *(uint4*)(op + 8) = *(const uint4*)&T[tl][cc + 8];
}

// ---------------------------------------------------------------------------
// prep_w: 4x W fp32 [d][c] -> bf16 [m][d][c]
// ---------------------------------------------------------------------------
__global__ __launch_bounds__(256) void prep_w_kernel(
    const float* __restrict__ Wq, const float* __restrict__ Wk,
    const float* __restrict__ Wv, const float* __restrict__ Wo,
    ushort* __restrict__ Wbf)
{
    const int idx = blockIdx.x * 256 + threadIdx.x;
    const int e4 = idx << 2;
    const int m = e4 >> 18;                 // / (512*512)
    const int off = e4 & ((1 << 18) - 1);
    const float* Ws[4] = {Wq, Wk, Wv, Wo};
    const float4 v = *(const float4*)(Ws[m] + off);
    ushort4 o;
    o.x = f2bf(v.x); o.y = f2bf(v.y); o.z = f2bf(v.z); o.w = f2bf(v.w);
    *(ushort4*)(Wbf + ((size_t)m << 18) + off) = o;
}

// ---------------------------------------------------------------------------
// proj_qkv: q,k token-major [b][t][d] bf16; v channel-major [b][d][t] bf16.
// q/k: D[t][d] = sum_c Z[t][c] W[d][c]  (A=Z, B=W)
// v:   D[d][t] = sum_c W[d][c] Z[t][c]  (A=W, B=Z)
// ---------------------------------------------------------------------------
__global__ __launch_bounds__(256) void proj_qkv_kernel(
    const ushort* __restrict__ Z, const ushort* __restrict__ Wbf,
    const float* __restrict__ phiq, const float* __restrict__ phik,
    const float* __restrict__ phiv,
    ushort* __restrict__ qre, ushort* __restrict__ qim,
    ushort* __restrict__ kre, ushort* __restrict__ kim,
    ushort* __restrict__ vre, ushort* __restrict__ vim)
{
    const int tid = threadIdx.x;
    const int t0 = blockIdx.x << 6;
    const int d0 = blockIdx.y << 6;
    const int b  = blockIdx.z;
    const size_t NE = (size_t)NB * NC * NT;
    const size_t zb = (size_t)b * NT * NC;
    const size_t bo = (size_t)b * NC * NT;

    __shared__ ushort Zs[2][64 * LDW];
    __shared__ ushort Wsh[3][64 * LDW];

    float4v accq[2][2][2] = {};
    float4v acck[2][2][2] = {};
    float4v accv[2][2][2] = {};

    const int lane = tid & 63;
    const int wA = ((tid >> 6) & 1) << 5;
    const int wB = ((tid >> 6) >> 1) << 5;
    const int l15 = lane & 15;
    const int quad = lane >> 4;
    const int row = tid >> 2, col8 = (tid & 3) << 3;

    for (int c0 = 0; c0 < NC; c0 += 32) {
        *(uint4*)&Zs[0][row * LDW + col8] =
            *(const uint4*)(Z + zb + (size_t)(t0 + row) * NC + c0 + col8);
        *(uint4*)&Zs[1][row * LDW + col8] =
            *(const uint4*)(Z + NE + zb + (size_t)(t0 + row) * NC + c0 + col8);
        #pragma unroll
        for (int m = 0; m < 3; ++m)
            *(uint4*)&Wsh[m][row * LDW + col8] =
                *(const uint4*)(Wbf + ((size_t)m << 18) + (size_t)(d0 + row) * NC + c0 + col8);
        __syncthreads();

        short8v zf[2][2], wf[3][2];
        #pragma unroll
        for (int i = 0; i < 2; ++i) {
            zf[0][i] = *(const short8v*)&Zs[0][(wA + i * 16 + l15) * LDW + quad * 8];
            zf[1][i] = *(const short8v*)&Zs[1][(wA + i * 16 + l15) * LDW + quad * 8];
        }
        #pragma unroll
        for (int m = 0; m < 3; ++m)
            #pragma unroll
            for (int j = 0; j < 2; ++j)
                wf[m][j] = *(const short8v*)&Wsh[m][(wB + j * 16 + l15) * LDW + quad * 8];

        #pragma unroll
        for (int cmp = 0; cmp < 2; ++cmp)
            #pragma unroll
            for (int i = 0; i < 2; ++i)
                #pragma unroll
                for (int j = 0; j < 2; ++j) {
                    accq[cmp][i][j] = MFMA_BF16(zf[cmp][i], wf[0][j], accq[cmp][i][j]);
                    acck[cmp][i][j] = MFMA_BF16(zf[cmp][i], wf[1][j], acck[cmp][i][j]);
                    accv[cmp][j][i] = MFMA_BF16(wf[2][j], zf[cmp][i], accv[cmp][j][i]);
                }
        __syncthreads();
    }

    // q/k epilogue: token-major; C/D: col=lane&15 (d), row=quad*4+r (t)
    #pragma unroll
    for (int j = 0; j < 2; ++j) {
        const int d = d0 + wB + j * 16 + l15;
        const float pq = phiq[d], pk = phik[d];
        const float cq = cosf(pq), sq = sinf(pq);
        const float ck = cosf(pk), sk = sinf(pk);
        #pragma unroll
        for (int i = 0; i < 2; ++i)
            #pragma unroll
            for (int r = 0; r < 4; ++r) {
                const int t = t0 + wA + i * 16 + quad * 4 + r;
                const size_t off = bo + (size_t)t * NC + d;
                const float qr2 = accq[0][i][j][r], qi2 = accq[1][i][j][r];
                qre[off] = f2bf(qr2 * cq - qi2 * sq);
                qim[off] = f2bf(qr2 * sq + qi2 * cq);
                const float kr2 = acck[0][i][j][r], ki2 = acck[1][i][j][r];
                kre[off] = f2bf(kr2 * ck - ki2 * sk);
                kim[off] = f2bf(kr2 * sk + ki2 * ck);
            }
    }
    // v epilogue: channel-major; col=lane&15 (t), row=quad*4+r (d)
    #pragma unroll
    for (int j = 0; j < 2; ++j)
        #pragma unroll
        for (int r = 0; r < 4; ++r) {
            const int d = d0 + wB + j * 16 + quad * 4 + r;
            const float pv_ = phiv[d];
            const float cv = cosf(pv_), sv = sinf(pv_);
            #pragma unroll
            for (int i = 0; i < 2; ++i) {
                const int t = t0 + wA + i * 16 + l15;
                const size_t off = bo + (size_t)d * NT + t;
                const float vr2 = accv[0][j][i][r], vi2 = accv[1][j][i][r];
                vre[off] = f2bf(vr2 * cv - vi2 * sv);
                vim[off] = f2bf(vr2 * sv + vi2 * cv);
            }
        }
}

// ---------------------------------------------------------------------------
// scores (full): S[b][t][u] = 0.125*(QreKre^T + QimKim^T); NEG_BIG above diag.
// ---------------------------------------------------------------------------
__global__ __launch_bounds__(256) void scores_mfma_kernel(
    const ushort* __restrict__ Qre, const ushort* __restrict__ Qim,
    const ushort* __restrict__ Kre, const ushort* __restrict__ Kim,
    float* __restrict__ S)
{
    const int u0 = blockIdx.x << 6;
    const int t0 = blockIdx.y << 6;
    if (u0 > t0) return;
    const int b = blockIdx.z;
    const int tid = threadIdx.x;
    const size_t bo = (size_t)b * NC * NT;

    __shared__ ushort Qs[2][64 * LDW];
    __shared__ ushort Ks[2][64 * LDW];
    float4v acc[2][2] = {};

    const int lane = tid & 63;
    const int wA = ((tid >> 6) & 1) << 5;
    const int wB = ((tid >> 6) >> 1) << 5;
    const int l15 = lane & 15;
    const int quad = lane >> 4;
    const int row = tid >> 2, col8 = (tid & 3) << 3;

    for (int c0 = 0; c0 < NC; c0 += 32) {
        *(uint4*)&Qs[0][row * LDW + col8] = *(const uint4*)(Qre + bo + (size_t)(t0 + row) * NC + c0 + col8);
        *(uint4*)&Qs[1][row * LDW + col8] = *(const uint4*)(Qim + bo + (size_t)(t0 + row) * NC + c0 + col8);
        *(uint4*)&Ks[0][row * LDW + col8] = *(const uint4*)(Kre + bo + (size_t)(u0 + row) * NC + c0 + col8);
        *(uint4*)&Ks[1][row * LDW + col8] = *(const uint4*)(Kim + bo + (size_t)(u0 + row) * NC + c0 + col8);
        __syncthreads();
        short8v qf[2][2], kf[2][2];
        #pragma unroll
        for (int i = 0; i < 2; ++i) {
            qf[0][i] = *(const short8v*)&Qs[0][(wA + i * 16 + l15) * LDW + quad * 8];
            qf[1][i] = *(const short8v*)&Qs[1][(wA + i * 16 + l15) * LDW + quad * 8];
            kf[0][i] = *(const short8v*)&Ks[0][(wB + i * 16 + l15) * LDW + quad * 8];
            kf[1][i] = *(const short8v*)&Ks[1][(wB + i * 16 + l15) * LDW + quad * 8];
        }
        #pragma unroll
        for (int i = 0; i < 2; ++i)
            #pragma unroll
            for (int j = 0; j < 2; ++j) {
                acc[i][j] = MFMA_BF16(qf[0][i], kf[0][j], acc[i][j]);
                acc[i][j] = MFMA_BF16(qf[1][i], kf[1][j], acc[i][j]);
            }
        __syncthreads();
    }
    #pragma unroll
    for (int i = 0; i < 2; ++i)
        #pragma unroll
        for (int j = 0; j < 2; ++j)
            #pragma unroll
            for (int r = 0; r < 4; ++r) {
                const int t = t0 + wA + i * 16 + quad * 4 + r;
                const int u = u0 + wB + j * 16 + l15;
                S[((size_t)b * NT + t) * NT + u] = (u > t) ? NEG_BIG : acc[i][j][r] * SCALE;
            }
}

// ---------------------------------------------------------------------------
// softmax (full rows, in place). Writes 0 for all masked columns, so the
// whole S row becomes defined even where scores skipped tiles.
// ---------------------------------------------------------------------------
__global__ __launch_bounds__(256) void softmax_kernel(float* __restrict__ S)
{
    const int t = blockIdx.x, b = blockIdx.y;
    float* row = S + ((size_t)b * NT + t) * NT;
    const int tid = threadIdx.x;
    const int u0 = tid << 2;
    const float4 sv = *(const float4*)(row + u0);
    const float s[4] = {sv.x, sv.y, sv.z, sv.w};

    float m = NEG_BIG;
    #pragma unroll
    for (int i = 0; i < 4; ++i) if (u0 + i <= t) m = fmaxf(m, s[i]);
    #pragma unroll
    for (int off = 32; off > 0; off >>= 1) m = fmaxf(m, __shfl_xor(m, off, 64));

    __shared__ float rm[4], rs[4];
    const int wv = tid >> 6, ln = tid & 63;
    if (ln == 0) rm[wv] = m;
    __syncthreads();
    m = fmaxf(fmaxf(rm[0], rm[1]), fmaxf(rm[2], rm[3]));

    float e[4]; float ls = 0.f;
    #pragma unroll
    for (int i = 0; i < 4; ++i) {
        e[i] = (u0 + i <= t) ? __expf(s[i] - m) : 0.f;
        ls += e[i];
    }
    #pragma unroll
    for (int off = 32; off > 0; off >>= 1) ls += __shfl_xor(ls, off, 64);
    if (ln == 0) rs[wv] = ls;
    __syncthreads();
    const float inv = 1.0f / (rs[0] + rs[1] + rs[2] + rs[3]);
    *(float4*)(row + u0) = make_float4(e[0] * inv, e[1] * inv, e[2] * inv, e[3] * inv);
}

// ---------------------------------------------------------------------------
// pv (full): O[t][c] = sum_u P[t][u] V[u][c]; A=P (fp32 S staged->bf16),
// B=V channel-major. O written token-major bf16 (aliases q buffers).
// ---------------------------------------------------------------------------
__global__ __launch_bounds__(256) void pv_mfma_kernel(
    const float* __restrict__ S,
    const ushort* __restrict__ Vre, const ushort* __restrict__ Vim,
    ushort* __restrict__ Ore, ushort* __restrict__ Oim)
{
    const int c0 = blockIdx.x << 6;
    const int t0 = blockIdx.y << 6;
    const int b = blockIdx.z;
    const int tid = threadIdx.x;
    const size_t bo = (size_t)b * NC * NT;
    const float* Sb = S + (size_t)b * NT * NT;

    __shared__ ushort Ps[64 * LDW];
    __shared__ ushort Vs[2][64 * LDW];
    float4v acc[2][2][2] = {};

    const int lane = tid & 63;
    const int wA = ((tid >> 6) & 1) << 5;
    const int wB = ((tid >> 6) >> 1) << 5;
    const int l15 = lane & 15;
    const int quad = lane >> 4;
    const int row = tid >> 2, col8 = (tid & 3) << 3;

    const int ulim = t0 + 64;
    for (int u0 = 0; u0 < ulim; u0 += 32) {
        {
            const float* sp = Sb + (size_t)(t0 + row) * NT + u0 + col8;
            const float4 a = *(const float4*)sp;
            const float4 b4 = *(const float4*)(sp + 4);
            short8v p8;
            p8[0] = (short)f2bf(a.x);  p8[1] = (short)f2bf(a.y);
            p8[2] = (short)f2bf(a.z);  p8[3] = (short)f2bf(a.w);
            p8[4] = (short)f2bf(b4.x); p8[5] = (short)f2bf(b4.y);
            p8[6] = (short)f2bf(b4.z); p8[7] = (short)f2bf(b4.w);
            *(short8v*)&Ps[row * LDW + col8] = p8;
        }
        *(uint4*)&Vs[0][row * LDW + col8] = *(const uint4*)(Vre + bo + (size_t)(c0 + row) * NT + u0 + col8);
        *(uint4*)&Vs[1][row * LDW + col8] = *(const uint4*)(Vim + bo + (size_t)(c0 + row) * NT + u0 + col8);
        __syncthreads();
        short8v pf[2], vf[2][2];
        #pragma unroll
        for (int i = 0; i < 2; ++i) {
            pf[i] = *(const short8v*)&Ps[(wA + i * 16 + l15) * LDW + quad * 8];
            vf[0][i] = *(const short8v*)&Vs[0][(wB + i * 16 + l15) * LDW + quad * 8];
            vf[1][i] = *(const short8v*)&Vs[1][(wB + i * 16 + l15) * LDW + quad * 8];
        }
        #pragma unroll
        for (int i = 0; i < 2; ++i)
            #pragma unroll
            for (int j = 0; j < 2; ++j) {
                acc[0][i][j] = MFMA_BF16(pf[i], vf[0][j], acc[0][i][j]);
                acc[1][i][j] = MFMA_BF16(pf[i], vf[1][j], acc[1][i][j]);
            }
        __syncthreads();
    }
    #pragma unroll
    for (int i = 0; i < 2; ++i)
        #pragma unroll
        for (int j = 0; j < 2; ++j)
            #pragma unroll
            for (int r = 0; r < 4; ++r) {
                const int t = t0 + wA + i * 16 + quad * 4 + r;
                const int c = c0 + wB + j * 16 + l15;
                const size_t off = bo + (size_t)t * NC + c;
                Ore[off] = f2bf(acc[0][i][j][r]);
                Oim[off] = f2bf(acc[1][i][j][r]);
            }
}

// ---------------------------------------------------------------------------
// proj_out: y[d][t] = rot( sum_c Wo[d][c] O[t][c], phi_o[d] ) -> fp32 d_out.
// A=Wo (from Wbf slot 3), B=O token-major bf16.
// ---------------------------------------------------------------------------
__global__ __launch_bounds__(256) void proj_out_kernel(
    const ushort* __restrict__ Ore, const ushort* __restrict__ Oim,
    const ushort* __restrict__ Wbf, const float* __restrict__ phio,
    float* __restrict__ outRe, float* __restrict__ outIm)
{
    const int d0 = blockIdx.x << 6;
    const int t0 = blockIdx.y << 6;
    const int b = blockIdx.z;
    const int tid = threadIdx.x;
    const size_t bo = (size_t)b * NC * NT;
    const ushort* Wo = Wbf + ((size_t)3 << 18);

    __shared__ ushort WoS[64 * LDW];
    __shared__ ushort Os[2][64 * LDW];
    float4v acc[2][2][2] = {};

    const int lane = tid & 63;
    const int wA = ((tid >> 6) & 1) << 5;   // d-half
    const int wB = ((tid >> 6) >> 1) << 5;  // t-half
    const int l15 = lane & 15;
    const int quad = lane >> 4;
    const int row = tid >> 2, col8 = (tid & 3) << 3;

    for (int c0 = 0; c0 < NC; c0 += 32) {
        *(uint4*)&WoS[row * LDW + col8] = *(const uint4*)(Wo + (size_t)(d0 + row) * NC + c0 + col8);
        *(uint4*)&Os[0][row * LDW + col8] = *(const uint4*)(Ore + bo + (size_t)(t0 + row) * NC + c0 + col8);
        *(uint4*)&Os[1][row * LDW + col8] = *(const uint4*)(Oim + bo + (size_t)(t0 + row) * NC + c0 + col8);
        __syncthreads();
        short8v wf[2], of[2][2];
        #pragma unroll
        for (int i = 0; i < 2; ++i) {
            wf[i] = *(const short8v*)&WoS[(wA + i * 16 + l15) * LDW + quad * 8];
            of[0][i] = *(const short8v*)&Os[0][(wB + i * 16 + l15) * LDW + quad * 8];
            of[1][i] = *(const short8v*)&Os[1][(wB + i * 16 + l15) * LDW + quad * 8];
        }
        #pragma unroll
        for (int i = 0; i < 2; ++i)
            #pragma unroll
            for (int j = 0; j < 2; ++j) {
                acc[0][i][j] = MFMA_BF16(wf[i], of[0][j], acc[0][i][j]);
                acc[1][i][j] = MFMA_BF16(wf[i], of[1][j], acc[1][i][j]);
            }
        __syncthreads();
    }
    #pragma unroll
    for (int i = 0; i < 2; ++i)
        #pragma unroll
        for (int r = 0; r < 4; ++r) {
            const int d = d0 + wA + i * 16 + quad * 4 + r;
            const float ph = phio[d];
            const float cs = cosf(ph), sn = sinf(ph);
            #pragma unroll
            for (int j = 0; j < 2; ++j) {
                const int t = t0 + wB + j * 16 + l15;
                const float re2 = acc[0][i][j][r], im2 = acc[1][i][j][r];
                const size_t off = bo + (size_t)d * NT + t;
                outRe[off] = re2 * cs - im2 * sn;
                outIm[off] = re2 * sn + im2 * cs;
            }
        }
}

extern "C" void kernel_launch(void* const* d_in, const int* in_sizes, int n_in,
                              void* d_out, int out_size, void* d_ws, size_t ws_size,
                              hipStream_t stream) {
    (void)in_sizes; (void)n_in; (void)out_size; (void)ws_size;
    const float* z_re  = (const float*)d_in[0];
    const float* z_im  = (const float*)d_in[1];
    const float* Wq    = (const float*)d_in[2];
    const float* phi_q = (const float*)d_in[3];
    const float* Wk    = (const float*)d_in[4];
    const float* phi_k = (const float*)d_in[5];
    const float* Wv    = (const float*)d_in[6];
    const float* phi_v = (const float*)d_in[7];
    const float* Wo    = (const float*)d_in[8];
    const float* phi_o = (const float*)d_in[9];

    const size_t NE = (size_t)NB * NC * NT;      // 4,194,304
    ushort* ws  = (ushort*)d_ws;
    ushort* qre = ws + 0 * NE; ushort* qim = ws + 1 * NE;   // aliased as O after scores
    ushort* kre = ws + 2 * NE; ushort* kim = ws + 3 * NE;
    ushort* vre = ws + 4 * NE; ushort* vim = ws + 5 * NE;   // channel-major
    ushort* Wbf = ws + 6 * NE;                              // 4x512x512 bf16 = 2 MiB
    // ws use: 48 MiB + 2 MiB = 50 MiB

    // d_out doubles as scratch until proj_out: Z (bf16, 16.8 MiB) then S (fp32, 33.5 MiB)
    ushort* Z = (ushort*)d_out;
    float*  S = (float*)d_out;

    const dim3 blk(256);
    hipLaunchKernelGGL(prep_z_kernel, dim3(NT / 64, NC / 64, NB * 2), blk, 0, stream, z_re, z_im, Z);
    hipLaunchKernelGGL(prep_w_kernel, dim3(1024), blk, 0, stream, Wq, Wk, Wv, Wo, Wbf);
    hipLaunchKernelGGL(proj_qkv_kernel, dim3(NT / 64, NC / 64, NB), blk, 0, stream,
                       Z, Wbf, phi_q, phi_k, phi_v, qre, qim, kre, kim, vre, vim);
    hipLaunchKernelGGL(scores_mfma_kernel, dim3(NT / 64, NT / 64, NB), blk, 0, stream,
                       qre, qim, kre, kim, S);
    hipLaunchKernelGGL(softmax_kernel, dim3(NT, NB), blk, 0, stream, S);
    hipLaunchKernelGGL(pv_mfma_kernel, dim3(NC / 64, NT / 64, NB), blk, 0, stream,
                       S, vre, vim, qre, qim);

    float* outRe = (float*)d_out;
    float* outIm = outRe + NE;
    hipLaunchKernelGGL(proj_out_kernel, dim3(NC / 64, NT / 64, NB), blk, 0, stream,
                       qre, qim, Wbf, phi_o, outRe, outIm);
}

// Round 6
// 255.558 us; speedup vs baseline: 3.9338x; 1.1258x over previous
//
#include <hip/hip_runtime.h>
#include <math.h>

#define NB 8
#define NC 512
#define NT 1024
#define BT (NB * NT)          // 8192 flattened (b,t) rows
#define SCALE 0.125f
#define NEG_BIG (-3.0e38f)

typedef __attribute__((ext_vector_type(8))) short short8v;   // 8 bf16 (A/B frag)
typedef __attribute__((ext_vector_type(4))) float float4v;   // C/D frag
#define MFMA_BF16(A, B, C) __builtin_amdgcn_mfma_f32_16x16x32_bf16(A, B, C, 0, 0, 0)

__device__ __forceinline__ ushort f2bf(float f) {
    union { float f; unsigned int i; } v; v.f = f;
    unsigned int r = v.i + 0x7FFFu + ((v.i >> 16) & 1u);  // RNE
    return (ushort)(r >> 16);
}

// LDS slot swizzle: global 16B-chunk s of row r stored at slot s ^ vswz(r&15).
// Makes every ds_read_b128 frag-read phase exactly 2-way bank aliased (free).
__device__ __forceinline__ int vswz(int r) { return (r & 3) ^ ((r >> 2) & 3); }

#if defined(__has_builtin)
#if __has_builtin(__builtin_amdgcn_global_load_lds)
#define HAS_GLDS 1
#endif
#endif

#ifdef HAS_GLDS
__device__ __forceinline__ void glds16(const ushort* g, ushort* l) {
    __builtin_amdgcn_global_load_lds(
        (const __attribute__((address_space(1))) unsigned int*)g,
        (__attribute__((address_space(3))) unsigned int*)l, 16, 0, 0);
}
#endif

// Stage a ROWSx32(short) tile from a row-major matrix (row stride rsShorts),
// swizzled. g points at [row0][c0]. 1KB per wave-issue (16 rows).
template<int ROWS>
__device__ __forceinline__ void stage(const ushort* __restrict__ g, int rsShorts,
                                      ushort* tile, int w, int lane) {
    const int r4 = lane >> 2;
    const int sl = (lane & 3) ^ vswz(r4);
    const ushort* gl = g + (size_t)r4 * rsShorts + sl * 8;
    const int ni = (ROWS == 128) ? 2 : 1;
    #pragma unroll
    for (int s = 0; s < ni; ++s) {
        const int issue = w * ni + s;
#ifdef HAS_GLDS
        glds16(gl + (size_t)issue * 16 * rsShorts, tile + issue * 512);
#else
        const uint4 v = *(const uint4*)(gl + (size_t)issue * 16 * rsShorts);
        *(uint4*)(tile + issue * 512 + lane * 8) = v;
#endif
    }
}

// ---------------------------------------------------------------------------
// prep_z: z fp32 [b][c][t] -> Z bf16 token-major [comp][bt][c]  (in d_out)
// ---------------------------------------------------------------------------
__global__ __launch_bounds__(256) void prep_z_kernel(
    const float* __restrict__ zre, const float* __restrict__ zim,
    ushort* __restrict__ Z)
{
    const int t0 = blockIdx.x << 6, c0 = blockIdx.y << 6;
    const int bz = blockIdx.z, b = bz & 7, comp = bz >> 3;
    const float* src = (comp ? zim : zre) + (size_t)b * NC * NT;
    ushort* dst = Z + (size_t)(comp * NB + b) * NT * NC;
    const int tid = threadIdx.x;

    __shared__ ushort T[64][72];
    #pragma unroll
    for (int r = 0; r < 4; ++r) {
        const int cl = (tid >> 4) + r * 16;
        const int t4 = (tid & 15) << 2;
        const float4 v = *(const float4*)(src + (size_t)(c0 + cl) * NT + t0 + t4);
        T[t4 + 0][cl] = f2bf(v.x); T[t4 + 1][cl] = f2bf(v.y);
        T[t4 + 2][cl] = f2bf(v.z); T[t4 + 3][cl] = f2bf(v.w);
    }
    __syncthreads();
    const int tl = tid >> 2, cc = (tid & 3) << 4;
    ushort* op = dst + (size_t)(t0 + tl) * NC + c0 + cc;
    *(uint4*)op       = *(const uint4*)&T[tl][cc];
    *(uint4*)(op + 8) = *(const uint4*)&T[tl][cc + 8];
}

// ---------------------------------------------------------------------------
// prep_w: 4x W fp32 [d][c] -> bf16 [m][d][c] (ws)
// ---------------------------------------------------------------------------
__global__ __launch_bounds__(256) void prep_w_kernel(
    const float* __restrict__ Wq, const float* __restrict__ Wk,
    const float* __restrict__ Wv, const float* __restrict__ Wo,
    ushort* __restrict__ Wbf)
{
    const int idx = blockIdx.x * 256 + threadIdx.x;
    const int e4 = idx << 2;
    const int m = e4 >> 18;
    const int off = e4 & ((1 << 18) - 1);
    const float* Ws[4] = {Wq, Wk, Wv, Wo};
    const float4 v = *(const float4*)(Ws[m] + off);
    ushort4 o;
    o.x = f2bf(v.x); o.y = f2bf(v.y); o.z = f2bf(v.z); o.w = f2bf(v.w);
    *(ushort4*)(Wbf + ((size_t)m << 18) + off) = o;
}

// ---------------------------------------------------------------------------
// proj_qk: tile 128(bt) x 64(d); wave 64x32 for q AND k, re+im.
// D[t][d] = sum_c Z[t][c] W[d][c]; z-frags shared across q/k (32 MFMA : 12 reads)
// ---------------------------------------------------------------------------
__global__ __launch_bounds__(256, 2) void proj_qk_kernel(
    const ushort* __restrict__ Z, const ushort* __restrict__ Wbf,
    const float* __restrict__ phiq, const float* __restrict__ phik,
    ushort* __restrict__ qre, ushort* __restrict__ qim,
    ushort* __restrict__ kre, ushort* __restrict__ kim)
{
    const int tid = threadIdx.x;
    const int m0 = blockIdx.x << 7;
    const int d0 = blockIdx.y << 6;
    const size_t NE = (size_t)BT * NC;

    __shared__ alignas(16) ushort Zr[128 * 32], Zi[128 * 32];
    __shared__ alignas(16) ushort Wq_s[64 * 32], Wk_s[64 * 32];

    float4v accq[2][4][2] = {};
    float4v acck[2][4][2] = {};

    const int w = tid >> 6, lane = tid & 63;
    const int l15 = lane & 15, quad = lane >> 4;
    const int wm = (w & 1) << 6;
    const int wn = (w >> 1) << 5;
    const int sq8 = (quad ^ vswz(l15)) << 3;

    for (int c0 = 0; c0 < NC; c0 += 32) {
        stage<128>(Z + (size_t)m0 * NC + c0, NC, Zr, w, lane);
        stage<128>(Z + NE + (size_t)m0 * NC + c0, NC, Zi, w, lane);
        stage<64>(Wbf + (size_t)d0 * NC + c0, NC, Wq_s, w, lane);
        stage<64>(Wbf + ((size_t)1 << 18) + (size_t)d0 * NC + c0, NC, Wk_s, w, lane);
        __syncthreads();
        short8v zf[2][4], wqf[2], wkf[2];
        #pragma unroll
        for (int i = 0; i < 4; ++i) {
            zf[0][i] = *(const short8v*)(Zr + (wm + i * 16 + l15) * 32 + sq8);
            zf[1][i] = *(const short8v*)(Zi + (wm + i * 16 + l15) * 32 + sq8);
        }
        #pragma unroll
        for (int j = 0; j < 2; ++j) {
            wqf[j] = *(const short8v*)(Wq_s + (wn + j * 16 + l15) * 32 + sq8);
            wkf[j] = *(const short8v*)(Wk_s + (wn + j * 16 + l15) * 32 + sq8);
        }
        #pragma unroll
        for (int c = 0; c < 2; ++c)
            #pragma unroll
            for (int i = 0; i < 4; ++i)
                #pragma unroll
                for (int j = 0; j < 2; ++j) {
                    accq[c][i][j] = MFMA_BF16(zf[c][i], wqf[j], accq[c][i][j]);
                    acck[c][i][j] = MFMA_BF16(zf[c][i], wkf[j], acck[c][i][j]);
                }
        __syncthreads();
    }

    #pragma unroll
    for (int j = 0; j < 2; ++j) {
        const int d = d0 + wn + j * 16 + l15;
        const float pq = phiq[d], pk = phik[d];
        const float cq = cosf(pq), sq = sinf(pq);
        const float ck = cosf(pk), sk = sinf(pk);
        #pragma unroll
        for (int i = 0; i < 4; ++i)
            #pragma unroll
            for (int r = 0; r < 4; ++r) {
                const size_t m = m0 + wm + i * 16 + quad * 4 + r;
                const size_t off = m * NC + d;
                const float ar = accq[0][i][j][r], ai = accq[1][i][j][r];
                qre[off] = f2bf(ar * cq - ai * sq);
                qim[off] = f2bf(ar * sq + ai * cq);
                const float br = acck[0][i][j][r], bi = acck[1][i][j][r];
                kre[off] = f2bf(br * ck - bi * sk);
                kim[off] = f2bf(br * sk + bi * ck);
            }
    }
}

// ---------------------------------------------------------------------------
// proj_v: tile 128(d) x 64(bt); wave 64x32, re+im. A=Wv, B=Z -> channel-major v.
// ---------------------------------------------------------------------------
__global__ __launch_bounds__(256, 2) void proj_v_kernel(
    const ushort* __restrict__ Z, const ushort* __restrict__ Wbf,
    const float* __restrict__ phiv,
    ushort* __restrict__ vre, ushort* __restrict__ vim)
{
    const int tid = threadIdx.x;
    const int d0 = blockIdx.x << 7;
    const int bt0 = blockIdx.y << 6;
    const size_t NE = (size_t)BT * NC;

    __shared__ alignas(16) ushort Wv_s[128 * 32], Zr[64 * 32], Zi[64 * 32];
    float4v acc[2][4][2] = {};

    const int w = tid >> 6, lane = tid & 63;
    const int l15 = lane & 15, quad = lane >> 4;
    const int wm = (w & 1) << 6;
    const int wn = (w >> 1) << 5;
    const int sq8 = (quad ^ vswz(l15)) << 3;

    for (int c0 = 0; c0 < NC; c0 += 32) {
        stage<128>(Wbf + ((size_t)2 << 18) + (size_t)d0 * NC + c0, NC, Wv_s, w, lane);
        stage<64>(Z + (size_t)bt0 * NC + c0, NC, Zr, w, lane);
        stage<64>(Z + NE + (size_t)bt0 * NC + c0, NC, Zi, w, lane);
        __syncthreads();
        short8v wvf[4], zf[2][2];
        #pragma unroll
        for (int i = 0; i < 4; ++i)
            wvf[i] = *(const short8v*)(Wv_s + (wm + i * 16 + l15) * 32 + sq8);
        #pragma unroll
        for (int j = 0; j < 2; ++j) {
            zf[0][j] = *(const short8v*)(Zr + (wn + j * 16 + l15) * 32 + sq8);
            zf[1][j] = *(const short8v*)(Zi + (wn + j * 16 + l15) * 32 + sq8);
        }
        #pragma unroll
        for (int c = 0; c < 2; ++c)
            #pragma unroll
            for (int i = 0; i < 4; ++i)
                #pragma unroll
                for (int j = 0; j < 2; ++j)
                    acc[c][i][j] = MFMA_BF16(wvf[i], zf[c][j], acc[c][i][j]);
        __syncthreads();
    }

    #pragma unroll
    for (int i = 0; i < 4; ++i)
        #pragma unroll
        for (int r = 0; r < 4; ++r) {
            const int d = d0 + wm + i * 16 + quad * 4 + r;
            const float ph = phiv[d];
            const float cs = cosf(ph), sn = sinf(ph);
            #pragma unroll
            for (int j = 0; j < 2; ++j) {
                const int bt = bt0 + wn + j * 16 + l15;
                const int b = bt >> 10, t = bt & 1023;
                const size_t off = (size_t)b * NC * NT + (size_t)d * NT + t;
                const float vr = acc[0][i][j][r], vi = acc[1][i][j][r];
                vre[off] = f2bf(vr * cs - vi * sn);
                vim[off] = f2bf(vr * sn + vi * cs);
            }
        }
}

// ---------------------------------------------------------------------------
// scores: tile 128(t) x 128(u); wave 64x64, single fused acc (re+im).
// ---------------------------------------------------------------------------
__global__ __launch_bounds__(256, 2) void scores_kernel(
    const ushort* __restrict__ qre, const ushort* __restrict__ qim,
    const ushort* __restrict__ kre, const ushort* __restrict__ kim,
    float* __restrict__ S)
{
    const int u0b = blockIdx.x << 7;
    const int t0b = blockIdx.y << 7;
    if (u0b > t0b) return;
    const int b = blockIdx.z;
    const int tid = threadIdx.x;
    const size_t qb = (size_t)b * NT * NC;

    __shared__ alignas(16) ushort Qr[128 * 32], Qi[128 * 32], Kr[128 * 32], Ki[128 * 32];
    float4v acc[4][4] = {};

    const int w = tid >> 6, lane = tid & 63;
    const int l15 = lane & 15, quad = lane >> 4;
    const int wm = (w & 1) << 6;
    const int wn = (w >> 1) << 6;
    const int sq8 = (quad ^ vswz(l15)) << 3;

    for (int c0 = 0; c0 < NC; c0 += 32) {
        stage<128>(qre + qb + (size_t)t0b * NC + c0, NC, Qr, w, lane);
        stage<128>(qim + qb + (size_t)t0b * NC + c0, NC, Qi, w, lane);
        stage<128>(kre + qb + (size_t)u0b * NC + c0, NC, Kr, w, lane);
        stage<128>(kim + qb + (size_t)u0b * NC + c0, NC, Ki, w, lane);
        __syncthreads();
        short8v qf[2][4], kf[2][4];
        #pragma unroll
        for (int i = 0; i < 4; ++i) {
            qf[0][i] = *(const short8v*)(Qr + (wm + i * 16 + l15) * 32 + sq8);
            qf[1][i] = *(const short8v*)(Qi + (wm + i * 16 + l15) * 32 + sq8);
            kf[0][i] = *(const short8v*)(Kr + (wn + i * 16 + l15) * 32 + sq8);
            kf[1][i] = *(const short8v*)(Ki + (wn + i * 16 + l15) * 32 + sq8);
        }
        #pragma unroll
        for (int i = 0; i < 4; ++i)
            #pragma unroll
            for (int j = 0; j < 4; ++j) {
                acc[i][j] = MFMA_BF16(qf[0][i], kf[0][j], acc[i][j]);
                acc[i][j] = MFMA_BF16(qf[1][i], kf[1][j], acc[i][j]);
            }
        __syncthreads();
    }
    #pragma unroll
    for (int i = 0; i < 4; ++i)
        #pragma unroll
        for (int j = 0; j < 4; ++j)
            #pragma unroll
            for (int r = 0; r < 4; ++r) {
                const int t = t0b + wm + i * 16 + quad * 4 + r;
                const int u = u0b + wn + j * 16 + l15;
                S[((size_t)b * NT + t) * NT + u] = (u > t) ? NEG_BIG : acc[i][j][r] * SCALE;
            }
}

// ---------------------------------------------------------------------------
// softmax: full row, index-masked u<=t; packs P to bf16 IN PLACE at row front.
// ---------------------------------------------------------------------------
__global__ __launch_bounds__(256) void softmax_kernel(float* __restrict__ S)
{
    const int t = blockIdx.x, b = blockIdx.y;
    float* row = S + ((size_t)b * NT + t) * NT;
    const int tid = threadIdx.x;
    const int u0 = tid << 2;
    const float4 sv = *(const float4*)(row + u0);
    const float s[4] = {sv.x, sv.y, sv.z, sv.w};

    float m = NEG_BIG;
    #pragma unroll
    for (int i = 0; i < 4; ++i) if (u0 + i <= t) m = fmaxf(m, s[i]);
    #pragma unroll
    for (int off = 32; off > 0; off >>= 1) m = fmaxf(m, __shfl_xor(m, off, 64));

    __shared__ float rm[4], rs[4];
    const int wv = tid >> 6, ln = tid & 63;
    if (ln == 0) rm[wv] = m;
    __syncthreads();
    m = fmaxf(fmaxf(rm[0], rm[1]), fmaxf(rm[2], rm[3]));

    float e[4]; float ls = 0.f;
    #pragma unroll
    for (int i = 0; i < 4; ++i) {
        e[i] = (u0 + i <= t) ? __expf(s[i] - m) : 0.f;
        ls += e[i];
    }
    #pragma unroll
    for (int off = 32; off > 0; off >>= 1) ls += __shfl_xor(ls, off, 64);
    if (ln == 0) rs[wv] = ls;
    __syncthreads();
    const float inv = 1.0f / (rs[0] + rs[1] + rs[2] + rs[3]);
    ushort4 ov;
    ov.x = f2bf(e[0] * inv); ov.y = f2bf(e[1] * inv);
    ov.z = f2bf(e[2] * inv); ov.w = f2bf(e[3] * inv);
    *(ushort4*)((ushort*)row + u0) = ov;   // all reads done before barriers above
}

// ---------------------------------------------------------------------------
// pv: tile 128(t) x 64(c); wave 64x32, re+im share A=P. B=V channel-major.
// O token-major bf16 (aliases q buffers). Causal: K-loop to t-tile end.
// ---------------------------------------------------------------------------
__global__ __launch_bounds__(256, 2) void pv_kernel(
    const float* __restrict__ S,
    const ushort* __restrict__ vre, const ushort* __restrict__ vim,
    ushort* __restrict__ Ore, ushort* __restrict__ Oim)
{
    const int c0b = blockIdx.x << 6;
    const int t0b = blockIdx.y << 7;
    const int b = blockIdx.z;
    const int tid = threadIdx.x;
    const ushort* P = (const ushort*)S + ((size_t)b * NT + t0b) * (NT * 2);
    const size_t vb = (size_t)b * NC * NT;

    __shared__ alignas(16) ushort Ps[128 * 32], Vr[64 * 32], Vi[64 * 32];
    float4v acc[2][4][2] = {};

    const int w = tid >> 6, lane = tid & 63;
    const int l15 = lane & 15, quad = lane >> 4;
    const int wm = (w & 1) << 6;
    const int wn = (w >> 1) << 5;
    const int sq8 = (quad ^ vswz(l15)) << 3;

    const int iters = (t0b + 128) >> 5;
    for (int it = 0; it < iters; ++it) {
        const int u0 = it << 5;
        stage<128>(P + u0, NT * 2, Ps, w, lane);
        stage<64>(vre + vb + (size_t)c0b * NT + u0, NT, Vr, w, lane);
        stage<64>(vim + vb + (size_t)c0b * NT + u0, NT, Vi, w, lane);
        __syncthreads();
        short8v pf[4], vf[2][2];
        #pragma unroll
        for (int i = 0; i < 4; ++i)
            pf[i] = *(const short8v*)(Ps + (wm + i * 16 + l15) * 32 + sq8);
        #pragma unroll
        for (int j = 0; j < 2; ++j) {
            vf[0][j] = *(const short8v*)(Vr + (wn + j * 16 + l15) * 32 + sq8);
            vf[1][j] = *(const short8v*)(Vi + (wn + j * 16 + l15) * 32 + sq8);
        }
        #pragma unroll
        for (int c = 0; c < 2; ++c)
            #pragma unroll
            for (int i = 0; i < 4; ++i)
                #pragma unroll
                for (int j = 0; j < 2; ++j)
                    acc[c][i][j] = MFMA_BF16(pf[i], vf[c][j], acc[c][i][j]);
        __syncthreads();
    }
    #pragma unroll
    for (int i = 0; i < 4; ++i)
        #pragma unroll
        for (int j = 0; j < 2; ++j)
            #pragma unroll
            for (int r = 0; r < 4; ++r) {
                const int t = t0b + wm + i * 16 + quad * 4 + r;
                const int c = c0b + wn + j * 16 + l15;
                const size_t off = ((size_t)b * NT + t) * NC + c;
                Ore[off] = f2bf(acc[0][i][j][r]);
                Oim[off] = f2bf(acc[1][i][j][r]);
            }
}

// ---------------------------------------------------------------------------
// proj_out: tile 128(d) x 64(bt); wave 64x32, re+im share A=Wo. fp32 -> d_out.
// ---------------------------------------------------------------------------
__global__ __launch_bounds__(256, 2) void proj_out_kernel(
    const ushort* __restrict__ Ore, const ushort* __restrict__ Oim,
    const ushort* __restrict__ Wbf, const float* __restrict__ phio,
    float* __restrict__ outRe, float* __restrict__ outIm)
{
    const int tid = threadIdx.x;
    const int d0 = blockIdx.x << 7;
    const int bt0 = blockIdx.y << 6;

    __shared__ alignas(16) ushort Wo_s[128 * 32], Or_s[64 * 32], Oi_s[64 * 32];
    float4v acc[2][4][2] = {};

    const int w = tid >> 6, lane = tid & 63;
    const int l15 = lane & 15, quad = lane >> 4;
    const int wm = (w & 1) << 6;
    const int wn = (w >> 1) << 5;
    const int sq8 = (quad ^ vswz(l15)) << 3;

    for (int c0 = 0; c0 < NC; c0 += 32) {
        stage<128>(Wbf + ((size_t)3 << 18) + (size_t)d0 * NC + c0, NC, Wo_s, w, lane);
        stage<64>(Ore + (size_t)bt0 * NC + c0, NC, Or_s, w, lane);
        stage<64>(Oim + (size_t)bt0 * NC + c0, NC, Oi_s, w, lane);
        __syncthreads();
        short8v wof[4], of[2][2];
        #pragma unroll
        for (int i = 0; i < 4; ++i)
            wof[i] = *(const short8v*)(Wo_s + (wm + i * 16 + l15) * 32 + sq8);
        #pragma unroll
        for (int j = 0; j < 2; ++j) {
            of[0][j] = *(const short8v*)(Or_s + (wn + j * 16 + l15) * 32 + sq8);
            of[1][j] = *(const short8v*)(Oi_s + (wn + j * 16 + l15) * 32 + sq8);
        }
        #pragma unroll
        for (int c = 0; c < 2; ++c)
            #pragma unroll
            for (int i = 0; i < 4; ++i)
                #pragma unroll
                for (int j = 0; j < 2; ++j)
                    acc[c][i][j] = MFMA_BF16(wof[i], of[c][j], acc[c][i][j]);
        __syncthreads();
    }

    #pragma unroll
    for (int i = 0; i < 4; ++i)
        #pragma unroll
        for (int r = 0; r < 4; ++r) {
            const int d = d0 + wm + i * 16 + quad * 4 + r;
            const float ph = phio[d];
            const float cs = cosf(ph), sn = sinf(ph);
            #pragma unroll
            for (int j = 0; j < 2; ++j) {
                const int bt = bt0 + wn + j * 16 + l15;
                const int b = bt >> 10, t = bt & 1023;
                const size_t off = (size_t)b * NC * NT + (size_t)d * NT + t;
                const float re2 = acc[0][i][j][r], im2 = acc[1][i][j][r];
                outRe[off] = re2 * cs - im2 * sn;
                outIm[off] = re2 * sn + im2 * cs;
            }
        }
}

extern "C" void kernel_launch(void* const* d_in, const int* in_sizes, int n_in,
                              void* d_out, int out_size, void* d_ws, size_t ws_size,
                              hipStream_t stream) {
    (void)in_sizes; (void)n_in; (void)out_size; (void)ws_size;
    const float* z_re  = (const float*)d_in[0];
    const float* z_im  = (const float*)d_in[1];
    const float* Wq    = (const float*)d_in[2];
    const float* phi_q = (const float*)d_in[3];
    const float* Wk    = (const float*)d_in[4];
    const float* phi_k = (const float*)d_in[5];
    const float* Wv    = (const float*)d_in[6];
    const float* phi_v = (const float*)d_in[7];
    const float* Wo    = (const float*)d_in[8];
    const float* phi_o = (const float*)d_in[9];

    const size_t NE = (size_t)BT * NC;     // 4,194,304
    ushort* ws  = (ushort*)d_ws;
    ushort* qre = ws + 0 * NE; ushort* qim = ws + 1 * NE;   // aliased as O after scores
    ushort* kre = ws + 2 * NE; ushort* kim = ws + 3 * NE;
    ushort* vre = ws + 4 * NE; ushort* vim = ws + 5 * NE;   // channel-major
    ushort* Wbf = ws + 6 * NE;                              // 2 MiB
    // ws: 50 MiB. d_out doubles as scratch: Z (16.8 MiB) then S (33.5 MiB).
    ushort* Z = (ushort*)d_out;
    float*  S = (float*)d_out;

    const dim3 blk(256);
    hipLaunchKernelGGL(prep_z_kernel, dim3(NT / 64, NC / 64, NB * 2), blk, 0, stream, z_re, z_im, Z);
    hipLaunchKernelGGL(prep_w_kernel, dim3(1024), blk, 0, stream, Wq, Wk, Wv, Wo, Wbf);
    hipLaunchKernelGGL(proj_qk_kernel, dim3(BT / 128, NC / 64), blk, 0, stream,
                       Z, Wbf, phi_q, phi_k, qre, qim, kre, kim);
    hipLaunchKernelGGL(proj_v_kernel, dim3(NC / 128, BT / 64), blk, 0, stream,
                       Z, Wbf, phi_v, vre, vim);
    hipLaunchKernelGGL(scores_kernel, dim3(NT / 128, NT / 128, NB), blk, 0, stream,
                       qre, qim, kre, kim, S);
    hipLaunchKernelGGL(softmax_kernel, dim3(NT, NB), blk, 0, stream, S);
    hipLaunchKernelGGL(pv_kernel, dim3(NC / 64, NT / 128, NB), blk, 0, stream,
                       S, vre, vim, qre, qim);
    hipLaunchKernelGGL(proj_out_kernel, dim3(NC / 128, BT / 64), blk, 0, stream,
                       qre, qim, Wbf, phi_o, (float*)d_out, (float*)d_out + NE);
}

// Round 7
// 239.166 us; speedup vs baseline: 4.2034x; 1.0685x over previous
//
#include <hip/hip_runtime.h>
#include <math.h>

#define NB 8
#define NC 512
#define NT 1024
#define BT (NB * NT)          // 8192 flattened (b,t) rows
#define SCALE 0.125f
#define NEG_BIG (-3.0e38f)

typedef __attribute__((ext_vector_type(8))) short short8v;   // 8 bf16 (A/B frag)
typedef __attribute__((ext_vector_type(4))) float float4v;   // C/D frag
#define MFMA_BF16(A, B, C) __builtin_amdgcn_mfma_f32_16x16x32_bf16(A, B, C, 0, 0, 0)

__device__ __forceinline__ ushort f2bf(float f) {
    union { float f; unsigned int i; } v; v.f = f;
    unsigned int r = v.i + 0x7FFFu + ((v.i >> 16) & 1u);  // RNE
    return (ushort)(r >> 16);
}

#if defined(__has_builtin)
#if __has_builtin(__builtin_amdgcn_global_load_lds)
#define HAS_GLDS 1
#endif
#endif

#ifdef HAS_GLDS
__device__ __forceinline__ void glds16(const ushort* g, ushort* l) {
    __builtin_amdgcn_global_load_lds(
        (const __attribute__((address_space(1))) unsigned int*)g,
        (__attribute__((address_space(3))) unsigned int*)l, 16, 0, 0);
}
#endif

// ---------------------------------------------------------------------------
// BK=64 tile: ROWS x 64 shorts (128B rows). LDS slot p of row r holds global
// 16B-chunk p ^ (r&7)  => every ds_read_b128 frag phase is 2-way (free, m136).
// One issue = 64 lanes x 16B = 8 rows. 4 waves cover ROWS/8 issues.
// ---------------------------------------------------------------------------
template<int ROWS>
__device__ __forceinline__ void stage64(const ushort* __restrict__ g, int rsShorts,
                                        ushort* tile, int w, int lane) {
    const int r8 = lane >> 3;                  // row within 8-row group
    const int ck = (lane & 7) ^ r8;            // global chunk fetched by this lane
    const ushort* gl = g + (size_t)r8 * rsShorts + (ck << 3);
    constexpr int ni = ROWS / 32;              // issues per wave
    #pragma unroll
    for (int s = 0; s < ni; ++s) {
        const int issue = w * ni + s;
#ifdef HAS_GLDS
        glds16(gl + (size_t)issue * 8 * rsShorts, tile + issue * 512);
#else
        const uint4 v = *(const uint4*)(gl + (size_t)issue * 8 * rsShorts);
        *(uint4*)(tile + issue * 512 + lane * 8) = v;
#endif
    }
}

// frag read: row rr (local), chunk q (0..7): swizzled address
__device__ __forceinline__ short8v frag(const ushort* tile, int rr, int q) {
    return *(const short8v*)(tile + rr * 64 + ((q ^ (rr & 7)) << 3));
}

// ---------------------------------------------------------------------------
// prep_z: z fp32 [b][c][t] -> Z bf16 token-major [comp][bt][c]  (in d_out)
// ---------------------------------------------------------------------------
__global__ __launch_bounds__(256) void prep_z_kernel(
    const float* __restrict__ zre, const float* __restrict__ zim,
    ushort* __restrict__ Z)
{
    const int t0 = blockIdx.x << 6, c0 = blockIdx.y << 6;
    const int bz = blockIdx.z, b = bz & 7, comp = bz >> 3;
    const float* src = (comp ? zim : zre) + (size_t)b * NC * NT;
    ushort* dst = Z + (size_t)(comp * NB + b) * NT * NC;
    const int tid = threadIdx.x;

    __shared__ ushort T[64][72];
    #pragma unroll
    for (int r = 0; r < 4; ++r) {
        const int cl = (tid >> 4) + r * 16;
        const int t4 = (tid & 15) << 2;
        const float4 v = *(const float4*)(src + (size_t)(c0 + cl) * NT + t0 + t4);
        T[t4 + 0][cl] = f2bf(v.x); T[t4 + 1][cl] = f2bf(v.y);
        T[t4 + 2][cl] = f2bf(v.z); T[t4 + 3][cl] = f2bf(v.w);
    }
    __syncthreads();
    const int tl = tid >> 2, cc = (tid & 3) << 4;
    ushort* op = dst + (size_t)(t0 + tl) * NC + c0 + cc;
    *(uint4*)op       = *(const uint4*)&T[tl][cc];
    *(uint4*)(op + 8) = *(const uint4*)&T[tl][cc + 8];
}

// ---------------------------------------------------------------------------
// prep_w: 4x W fp32 [d][c] -> bf16 [m][d][c] (ws)
// ---------------------------------------------------------------------------
__global__ __launch_bounds__(256) void prep_w_kernel(
    const float* __restrict__ Wq, const float* __restrict__ Wk,
    const float* __restrict__ Wv, const float* __restrict__ Wo,
    ushort* __restrict__ Wbf)
{
    const int idx = blockIdx.x * 256 + threadIdx.x;
    const int e4 = idx << 2;
    const int m = e4 >> 18;
    const int off = e4 & ((1 << 18) - 1);
    const float* Ws[4] = {Wq, Wk, Wv, Wo};
    const float4 v = *(const float4*)(Ws[m] + off);
    ushort4 o;
    o.x = f2bf(v.x); o.y = f2bf(v.y); o.z = f2bf(v.z); o.w = f2bf(v.w);
    *(ushort4*)(Wbf + ((size_t)m << 18) + off) = o;
}

// ---------------------------------------------------------------------------
// proj_qk: tile 128(bt) x 64(d); wave 64x32 computes q AND k, re+im.
// ---------------------------------------------------------------------------
__global__ __launch_bounds__(256, 2) void proj_qk_kernel(
    const ushort* __restrict__ Z, const ushort* __restrict__ Wbf,
    const float* __restrict__ phiq, const float* __restrict__ phik,
    ushort* __restrict__ qre, ushort* __restrict__ qim,
    ushort* __restrict__ kre, ushort* __restrict__ kim)
{
    const int tid = threadIdx.x;
    const int m0 = blockIdx.x << 7;
    const int d0 = blockIdx.y << 6;
    const size_t NE = (size_t)BT * NC;

    __shared__ alignas(16) ushort Zr[128 * 64], Zi[128 * 64];
    __shared__ alignas(16) ushort Wq_s[64 * 64], Wk_s[64 * 64];

    float4v accq[2][4][2] = {};
    float4v acck[2][4][2] = {};

    const int w = tid >> 6, lane = tid & 63;
    const int l15 = lane & 15, quad = lane >> 4;
    const int wm = (w & 1) << 6;
    const int wn = (w >> 1) << 5;

    for (int c0 = 0; c0 < NC; c0 += 64) {
        stage64<128>(Z + (size_t)m0 * NC + c0, NC, Zr, w, lane);
        stage64<128>(Z + NE + (size_t)m0 * NC + c0, NC, Zi, w, lane);
        stage64<64>(Wbf + (size_t)d0 * NC + c0, NC, Wq_s, w, lane);
        stage64<64>(Wbf + ((size_t)1 << 18) + (size_t)d0 * NC + c0, NC, Wk_s, w, lane);
        __syncthreads();
        #pragma unroll
        for (int kk = 0; kk < 2; ++kk) {
            const int q0 = kk * 4 + quad;
            short8v zf[2][4], wqf[2], wkf[2];
            #pragma unroll
            for (int i = 0; i < 4; ++i) {
                zf[0][i] = frag(Zr, wm + i * 16 + l15, q0);
                zf[1][i] = frag(Zi, wm + i * 16 + l15, q0);
            }
            #pragma unroll
            for (int j = 0; j < 2; ++j) {
                wqf[j] = frag(Wq_s, wn + j * 16 + l15, q0);
                wkf[j] = frag(Wk_s, wn + j * 16 + l15, q0);
            }
            #pragma unroll
            for (int c = 0; c < 2; ++c)
                #pragma unroll
                for (int i = 0; i < 4; ++i)
                    #pragma unroll
                    for (int j = 0; j < 2; ++j) {
                        accq[c][i][j] = MFMA_BF16(zf[c][i], wqf[j], accq[c][i][j]);
                        acck[c][i][j] = MFMA_BF16(zf[c][i], wkf[j], acck[c][i][j]);
                    }
        }
        __syncthreads();
    }

    #pragma unroll
    for (int j = 0; j < 2; ++j) {
        const int d = d0 + wn + j * 16 + l15;
        const float pq = phiq[d], pk = phik[d];
        const float cq = cosf(pq), sq = sinf(pq);
        const float ck = cosf(pk), sk = sinf(pk);
        #pragma unroll
        for (int i = 0; i < 4; ++i)
            #pragma unroll
            for (int r = 0; r < 4; ++r) {
                const size_t m = m0 + wm + i * 16 + quad * 4 + r;
                const size_t off = m * NC + d;
                const float ar = accq[0][i][j][r], ai = accq[1][i][j][r];
                qre[off] = f2bf(ar * cq - ai * sq);
                qim[off] = f2bf(ar * sq + ai * cq);
                const float br = acck[0][i][j][r], bi = acck[1][i][j][r];
                kre[off] = f2bf(br * ck - bi * sk);
                kim[off] = f2bf(br * sk + bi * ck);
            }
    }
}

// ---------------------------------------------------------------------------
// proj_v: tile 128(d) x 64(bt); A=Wv, B=Z -> channel-major v, re+im.
// ---------------------------------------------------------------------------
__global__ __launch_bounds__(256, 3) void proj_v_kernel(
    const ushort* __restrict__ Z, const ushort* __restrict__ Wbf,
    const float* __restrict__ phiv,
    ushort* __restrict__ vre, ushort* __restrict__ vim)
{
    const int tid = threadIdx.x;
    const int d0 = blockIdx.x << 7;
    const int bt0 = blockIdx.y << 6;
    const size_t NE = (size_t)BT * NC;

    __shared__ alignas(16) ushort Wv_s[128 * 64], Zr[64 * 64], Zi[64 * 64];
    float4v acc[2][4][2] = {};

    const int w = tid >> 6, lane = tid & 63;
    const int l15 = lane & 15, quad = lane >> 4;
    const int wm = (w & 1) << 6;
    const int wn = (w >> 1) << 5;

    for (int c0 = 0; c0 < NC; c0 += 64) {
        stage64<128>(Wbf + ((size_t)2 << 18) + (size_t)d0 * NC + c0, NC, Wv_s, w, lane);
        stage64<64>(Z + (size_t)bt0 * NC + c0, NC, Zr, w, lane);
        stage64<64>(Z + NE + (size_t)bt0 * NC + c0, NC, Zi, w, lane);
        __syncthreads();
        #pragma unroll
        for (int kk = 0; kk < 2; ++kk) {
            const int q0 = kk * 4 + quad;
            short8v wvf[4], zf[2][2];
            #pragma unroll
            for (int i = 0; i < 4; ++i)
                wvf[i] = frag(Wv_s, wm + i * 16 + l15, q0);
            #pragma unroll
            for (int j = 0; j < 2; ++j) {
                zf[0][j] = frag(Zr, wn + j * 16 + l15, q0);
                zf[1][j] = frag(Zi, wn + j * 16 + l15, q0);
            }
            #pragma unroll
            for (int c = 0; c < 2; ++c)
                #pragma unroll
                for (int i = 0; i < 4; ++i)
                    #pragma unroll
                    for (int j = 0; j < 2; ++j)
                        acc[c][i][j] = MFMA_BF16(wvf[i], zf[c][j], acc[c][i][j]);
        }
        __syncthreads();
    }

    #pragma unroll
    for (int i = 0; i < 4; ++i)
        #pragma unroll
        for (int r = 0; r < 4; ++r) {
            const int d = d0 + wm + i * 16 + quad * 4 + r;
            const float ph = phiv[d];
            const float cs = cosf(ph), sn = sinf(ph);
            #pragma unroll
            for (int j = 0; j < 2; ++j) {
                const int bt = bt0 + wn + j * 16 + l15;
                const int b = bt >> 10, t = bt & 1023;
                const size_t off = (size_t)b * NC * NT + (size_t)d * NT + t;
                const float vr = acc[0][i][j][r], vi = acc[1][i][j][r];
                vre[off] = f2bf(vr * cs - vi * sn);
                vim[off] = f2bf(vr * sn + vi * cs);
            }
        }
}

// ---------------------------------------------------------------------------
// scores: tile 128(t) x 128(u); heavy t-tiles first; fused re+im acc.
// ---------------------------------------------------------------------------
__global__ __launch_bounds__(256, 3) void scores_kernel(
    const ushort* __restrict__ qre, const ushort* __restrict__ qim,
    const ushort* __restrict__ kre, const ushort* __restrict__ kim,
    float* __restrict__ S)
{
    const int u0b = blockIdx.x << 7;
    const int t0b = (gridDim.y - 1 - blockIdx.y) << 7;   // heavy first
    if (u0b > t0b) return;
    const int b = blockIdx.z;
    const int tid = threadIdx.x;
    const size_t qb = (size_t)b * NT * NC;

    __shared__ alignas(16) ushort Qr[128 * 64], Qi[128 * 64], Kr[128 * 64], Ki[128 * 64];
    float4v acc[4][4] = {};

    const int w = tid >> 6, lane = tid & 63;
    const int l15 = lane & 15, quad = lane >> 4;
    const int wm = (w & 1) << 6;
    const int wn = (w >> 1) << 6;

    for (int c0 = 0; c0 < NC; c0 += 64) {
        stage64<128>(qre + qb + (size_t)t0b * NC + c0, NC, Qr, w, lane);
        stage64<128>(qim + qb + (size_t)t0b * NC + c0, NC, Qi, w, lane);
        stage64<128>(kre + qb + (size_t)u0b * NC + c0, NC, Kr, w, lane);
        stage64<128>(kim + qb + (size_t)u0b * NC + c0, NC, Ki, w, lane);
        __syncthreads();
        #pragma unroll
        for (int kk = 0; kk < 2; ++kk) {
            const int q0 = kk * 4 + quad;
            short8v qf[2][4], kf[2][4];
            #pragma unroll
            for (int i = 0; i < 4; ++i) {
                qf[0][i] = frag(Qr, wm + i * 16 + l15, q0);
                qf[1][i] = frag(Qi, wm + i * 16 + l15, q0);
                kf[0][i] = frag(Kr, wn + i * 16 + l15, q0);
                kf[1][i] = frag(Ki, wn + i * 16 + l15, q0);
            }
            #pragma unroll
            for (int i = 0; i < 4; ++i)
                #pragma unroll
                for (int j = 0; j < 4; ++j) {
                    acc[i][j] = MFMA_BF16(qf[0][i], kf[0][j], acc[i][j]);
                    acc[i][j] = MFMA_BF16(qf[1][i], kf[1][j], acc[i][j]);
                }
        }
        __syncthreads();
    }
    #pragma unroll
    for (int i = 0; i < 4; ++i)
        #pragma unroll
        for (int j = 0; j < 4; ++j)
            #pragma unroll
            for (int r = 0; r < 4; ++r) {
                const int t = t0b + wm + i * 16 + quad * 4 + r;
                const int u = u0b + wn + j * 16 + l15;
                S[((size_t)b * NT + t) * NT + u] = (u > t) ? NEG_BIG : acc[i][j][r] * SCALE;
            }
}

// ---------------------------------------------------------------------------
// softmax: full row, index-masked u<=t; packs P to bf16 IN PLACE at row front.
// ---------------------------------------------------------------------------
__global__ __launch_bounds__(256) void softmax_kernel(float* __restrict__ S)
{
    const int t = blockIdx.x, b = blockIdx.y;
    float* row = S + ((size_t)b * NT + t) * NT;
    const int tid = threadIdx.x;
    const int u0 = tid << 2;
    const float4 sv = *(const float4*)(row + u0);
    const float s[4] = {sv.x, sv.y, sv.z, sv.w};

    float m = NEG_BIG;
    #pragma unroll
    for (int i = 0; i < 4; ++i) if (u0 + i <= t) m = fmaxf(m, s[i]);
    #pragma unroll
    for (int off = 32; off > 0; off >>= 1) m = fmaxf(m, __shfl_xor(m, off, 64));

    __shared__ float rm[4], rs[4];
    const int wv = tid >> 6, ln = tid & 63;
    if (ln == 0) rm[wv] = m;
    __syncthreads();
    m = fmaxf(fmaxf(rm[0], rm[1]), fmaxf(rm[2], rm[3]));

    float e[4]; float ls = 0.f;
    #pragma unroll
    for (int i = 0; i < 4; ++i) {
        e[i] = (u0 + i <= t) ? __expf(s[i] - m) : 0.f;
        ls += e[i];
    }
    #pragma unroll
    for (int off = 32; off > 0; off >>= 1) ls += __shfl_xor(ls, off, 64);
    if (ln == 0) rs[wv] = ls;
    __syncthreads();
    const float inv = 1.0f / (rs[0] + rs[1] + rs[2] + rs[3]);
    ushort4 ov;
    ov.x = f2bf(e[0] * inv); ov.y = f2bf(e[1] * inv);
    ov.z = f2bf(e[2] * inv); ov.w = f2bf(e[3] * inv);
    *(ushort4*)((ushort*)row + u0) = ov;
}

// ---------------------------------------------------------------------------
// pv: tile 128(t) x 64(c); heavy t-tiles first; A=P, B=V channel-major.
// ---------------------------------------------------------------------------
__global__ __launch_bounds__(256, 3) void pv_kernel(
    const float* __restrict__ S,
    const ushort* __restrict__ vre, const ushort* __restrict__ vim,
    ushort* __restrict__ Ore, ushort* __restrict__ Oim)
{
    const int c0b = blockIdx.x << 6;
    const int t0b = (gridDim.y - 1 - blockIdx.y) << 7;   // heavy first
    const int b = blockIdx.z;
    const int tid = threadIdx.x;
    const ushort* P = (const ushort*)S + ((size_t)b * NT + t0b) * (NT * 2);
    const size_t vb = (size_t)b * NC * NT;

    __shared__ alignas(16) ushort Ps[128 * 64], Vr[64 * 64], Vi[64 * 64];
    float4v acc[2][4][2] = {};

    const int w = tid >> 6, lane = tid & 63;
    const int l15 = lane & 15, quad = lane >> 4;
    const int wm = (w & 1) << 6;
    const int wn = (w >> 1) << 5;

    const int iters = (t0b + 128) >> 6;
    for (int it = 0; it < iters; ++it) {
        const int u0 = it << 6;
        stage64<128>(P + u0, NT * 2, Ps, w, lane);
        stage64<64>(vre + vb + (size_t)c0b * NT + u0, NT, Vr, w, lane);
        stage64<64>(vim + vb + (size_t)c0b * NT + u0, NT, Vi, w, lane);
        __syncthreads();
        #pragma unroll
        for (int kk = 0; kk < 2; ++kk) {
            const int q0 = kk * 4 + quad;
            short8v pf[4], vf[2][2];
            #pragma unroll
            for (int i = 0; i < 4; ++i)
                pf[i] = frag(Ps, wm + i * 16 + l15, q0);
            #pragma unroll
            for (int j = 0; j < 2; ++j) {
                vf[0][j] = frag(Vr, wn + j * 16 + l15, q0);
                vf[1][j] = frag(Vi, wn + j * 16 + l15, q0);
            }
            #pragma unroll
            for (int c = 0; c < 2; ++c)
                #pragma unroll
                for (int i = 0; i < 4; ++i)
                    #pragma unroll
                    for (int j = 0; j < 2; ++j)
                        acc[c][i][j] = MFMA_BF16(pf[i], vf[c][j], acc[c][i][j]);
        }
        __syncthreads();
    }
    #pragma unroll
    for (int i = 0; i < 4; ++i)
        #pragma unroll
        for (int j = 0; j < 2; ++j)
            #pragma unroll
            for (int r = 0; r < 4; ++r) {
                const int t = t0b + wm + i * 16 + quad * 4 + r;
                const int c = c0b + wn + j * 16 + l15;
                const size_t off = ((size_t)b * NT + t) * NC + c;
                Ore[off] = f2bf(acc[0][i][j][r]);
                Oim[off] = f2bf(acc[1][i][j][r]);
            }
}

// ---------------------------------------------------------------------------
// proj_out: tile 128(d) x 64(bt); A=Wo, B=O. fp32 -> d_out [b][d][t].
// ---------------------------------------------------------------------------
__global__ __launch_bounds__(256, 3) void proj_out_kernel(
    const ushort* __restrict__ Ore, const ushort* __restrict__ Oim,
    const ushort* __restrict__ Wbf, const float* __restrict__ phio,
    float* __restrict__ outRe, float* __restrict__ outIm)
{
    const int tid = threadIdx.x;
    const int d0 = blockIdx.x << 7;
    const int bt0 = blockIdx.y << 6;

    __shared__ alignas(16) ushort Wo_s[128 * 64], Or_s[64 * 64], Oi_s[64 * 64];
    float4v acc[2][4][2] = {};

    const int w = tid >> 6, lane = tid & 63;
    const int l15 = lane & 15, quad = lane >> 4;
    const int wm = (w & 1) << 6;
    const int wn = (w >> 1) << 5;

    for (int c0 = 0; c0 < NC; c0 += 64) {
        stage64<128>(Wbf + ((size_t)3 << 18) + (size_t)d0 * NC + c0, NC, Wo_s, w, lane);
        stage64<64>(Ore + (size_t)bt0 * NC + c0, NC, Or_s, w, lane);
        stage64<64>(Oim + (size_t)bt0 * NC + c0, NC, Oi_s, w, lane);
        __syncthreads();
        #pragma unroll
        for (int kk = 0; kk < 2; ++kk) {
            const int q0 = kk * 4 + quad;
            short8v wof[4], of[2][2];
            #pragma unroll
            for (int i = 0; i < 4; ++i)
                wof[i] = frag(Wo_s, wm + i * 16 + l15, q0);
            #pragma unroll
            for (int j = 0; j < 2; ++j) {
                of[0][j] = frag(Or_s, wn + j * 16 + l15, q0);
                of[1][j] = frag(Oi_s, wn + j * 16 + l15, q0);
            }
            #pragma unroll
            for (int c = 0; c < 2; ++c)
                #pragma unroll
                for (int i = 0; i < 4; ++i)
                    #pragma unroll
                    for (int j = 0; j < 2; ++j)
                        acc[c][i][j] = MFMA_BF16(wof[i], of[c][j], acc[c][i][j]);
        }
        __syncthreads();
    }

    #pragma unroll
    for (int i = 0; i < 4; ++i)
        #pragma unroll
        for (int r = 0; r < 4; ++r) {
            const int d = d0 + wm + i * 16 + quad * 4 + r;
            const float ph = phio[d];
            const float cs = cosf(ph), sn = sinf(ph);
            #pragma unroll
            for (int j = 0; j < 2; ++j) {
                const int bt = bt0 + wn + j * 16 + l15;
                const int b = bt >> 10, t = bt & 1023;
                const size_t off = (size_t)b * NC * NT + (size_t)d * NT + t;
                const float re2 = acc[0][i][j][r], im2 = acc[1][i][j][r];
                outRe[off] = re2 * cs - im2 * sn;
                outIm[off] = re2 * sn + im2 * cs;
            }
        }
}

extern "C" void kernel_launch(void* const* d_in, const int* in_sizes, int n_in,
                              void* d_out, int out_size, void* d_ws, size_t ws_size,
                              hipStream_t stream) {
    (void)in_sizes; (void)n_in; (void)out_size; (void)ws_size;
    const float* z_re  = (const float*)d_in[0];
    const float* z_im  = (const float*)d_in[1];
    const float* Wq    = (const float*)d_in[2];
    const float* phi_q = (const float*)d_in[3];
    const float* Wk    = (const float*)d_in[4];
    const float* phi_k = (const float*)d_in[5];
    const float* Wv    = (const float*)d_in[6];
    const float* phi_v = (const float*)d_in[7];
    const float* Wo    = (const float*)d_in[8];
    const float* phi_o = (const float*)d_in[9];

    const size_t NE = (size_t)BT * NC;     // 4,194,304
    ushort* ws  = (ushort*)d_ws;
    ushort* qre = ws + 0 * NE; ushort* qim = ws + 1 * NE;   // aliased as O after scores
    ushort* kre = ws + 2 * NE; ushort* kim = ws + 3 * NE;
    ushort* vre = ws + 4 * NE; ushort* vim = ws + 5 * NE;   // channel-major
    ushort* Wbf = ws + 6 * NE;                              // 2 MiB
    // ws: 50 MiB. d_out doubles as scratch: Z (16.8 MiB) then S (33.5 MiB).
    ushort* Z = (ushort*)d_out;
    float*  S = (float*)d_out;

    const dim3 blk(256);
    hipLaunchKernelGGL(prep_z_kernel, dim3(NT / 64, NC / 64, NB * 2), blk, 0, stream, z_re, z_im, Z);
    hipLaunchKernelGGL(prep_w_kernel, dim3(1024), blk, 0, stream, Wq, Wk, Wv, Wo, Wbf);
    hipLaunchKernelGGL(proj_qk_kernel, dim3(BT / 128, NC / 64), blk, 0, stream,
                       Z, Wbf, phi_q, phi_k, qre, qim, kre, kim);
    hipLaunchKernelGGL(proj_v_kernel, dim3(NC / 128, BT / 64), blk, 0, stream,
                       Z, Wbf, phi_v, vre, vim);
    hipLaunchKernelGGL(scores_kernel, dim3(NT / 128, NT / 128, NB), blk, 0, stream,
                       qre, qim, kre, kim, S);
    hipLaunchKernelGGL(softmax_kernel, dim3(NT, NB), blk, 0, stream, S);
    hipLaunchKernelGGL(pv_kernel, dim3(NC / 64, NT / 128, NB), blk, 0, stream,
                       S, vre, vim, qre, qim);
    hipLaunchKernelGGL(proj_out_kernel, dim3(NC / 128, BT / 64), blk, 0, stream,
                       qre, qim, Wbf, phi_o, (float*)d_out, (float*)d_out + NE);
}